// Round 12
// baseline (373.363 us; speedup 1.0000x reference)
//
#include <hip/hip_runtime.h>

using bf16   = __bf16;
using bf16x4 = __attribute__((ext_vector_type(4))) __bf16;
using bf16x8 = __attribute__((ext_vector_type(8))) __bf16;
using f32x4  = __attribute__((ext_vector_type(4))) float;
using u32x4  = __attribute__((ext_vector_type(4))) unsigned int;

#define MFMA16(a,b,c) __builtin_amdgcn_mfma_f32_16x16x32_bf16((a),(b),(c),0,0,0)

__device__ inline void glds16(const void* g, void* l) {
    __builtin_amdgcn_global_load_lds(
        (__attribute__((address_space(1))) void*)(const_cast<void*>(g)),
        (__attribute__((address_space(3))) void*)(l), 16, 0, 0);
}

// bijective XCD-chunked remap (m204)
__device__ inline int xcd_remap(int bid, int nwg) {
    const int xcd = bid & 7, loc = bid >> 3;
    const int q8 = nwg >> 3, r8 = nwg & 7;
    return (xcd < r8 ? xcd * (q8 + 1) : r8 * (q8 + 1) + (xcd - r8) * q8) + loc;
}

// ---------------- constants ----------------
constexpr int CB   = 8;
constexpr int NH   = 12;
constexpr int CC   = 768;
constexpr int HD   = 64;
constexpr int TT   = 8, HH = 28, WW = 28;
constexpr int NTOK = TT*HH*WW + 1;      // 6273
constexpr int MX   = CB*NTOK;           // 50184
constexpr int MXP  = 50304;
constexpr int NQ   = 1569, NQP = 1600;
constexpr int NK   = 393,  NKP = 416;
constexpr int MO   = CB*NQ;             // 12552
constexpr int MOP  = 12672;
constexpr int CTOK = 1 + TT*20*20;      // 3201
constexpr int MKV  = CB*CTOK;           // 25608
constexpr int MKVP = 25856;

// ---------------- f32 -> bf16 cast (zero tail pad) ----------------
__global__ __launch_bounds__(256) void cast_f32_bf16(const float* __restrict__ src,
                                                     bf16* __restrict__ dst,
                                                     int nvalid, int ntotal) {
    int i = (blockIdx.x * 256 + threadIdx.x) * 4;
    int stride = gridDim.x * 256 * 4;
    for (; i < ntotal; i += stride) {
        bf16x4 o;
        if (i + 3 < nvalid) {
            f32x4 v = *(const f32x4*)(src + i);
            #pragma unroll
            for (int e = 0; e < 4; ++e) o[e] = (bf16)v[e];
        } else {
            #pragma unroll
            for (int e = 0; e < 4; ++e) {
                int k = i + e;
                o[e] = (bf16)((k < nvalid) ? src[k] : 0.f);
            }
        }
        *(bf16x4*)(dst + i) = o;
    }
}

// ---------------- merged prep: weight cast (2304 blks) + wt transpose (21) + bound (1) ----------------
__global__ __launch_bounds__(256) void prep(const float* __restrict__ Wq, const float* __restrict__ Wk,
                                            const float* __restrict__ Wv, const float* __restrict__ Wp,
                                            const float* __restrict__ pqw, const float* __restrict__ pkw,
                                            const float* __restrict__ pvw,
                                            const float* __restrict__ gq, const float* __restrict__ bq,
                                            const float* __restrict__ gk, const float* __restrict__ bk,
                                            bf16* __restrict__ wdst, float* __restrict__ wt,
                                            float* __restrict__ Mb) {
    constexpr int WSZ = 589824;
    const int bid = blockIdx.x, tid = threadIdx.x;
    if (bid < 2304) {
        int i = (bid * 256 + tid) * 4;
        const int setn = i / WSZ, j = i % WSZ;
        const float* src = (setn == 0) ? Wq : (setn == 1) ? Wk : (setn == 2) ? Wv : Wp;
        f32x4 v = *(const f32x4*)(src + j);
        bf16x4 o;
        #pragma unroll
        for (int e = 0; e < 4; ++e) o[e] = (bf16)v[e];
        *(bf16x4*)(wdst + i) = o;
    } else if (bid < 2325) {
        int i = (bid - 2304) * 256 + tid;
        if (i < 3 * 1728) {
            int setn = i / 1728, j = i % 1728;
            const float* src = (setn == 0) ? pqw : (setn == 1) ? pkw : pvw;
            int tap = j / 64, c = j % 64;
            wt[i] = src[c * 27 + tap];
        }
    } else if (tid < 64) {
        const int c = tid;
        float mgq = fabsf(gq[c]), sbq = bq[c] * bq[c];
        float mgk = fabsf(gk[c]), sbk = bk[c] * bk[c];
        #pragma unroll
        for (int m = 1; m < 64; m <<= 1) {
            mgq = fmaxf(mgq, __shfl_xor(mgq, m)); sbq += __shfl_xor(sbq, m);
            mgk = fmaxf(mgk, __shfl_xor(mgk, m)); sbk += __shfl_xor(sbk, m);
        }
        if (c == 0) {
            const float Bq = 8.f * mgq + sqrtf(sbq);
            const float Bk = 8.f * mgk + sqrtf(sbk);
            Mb[0] = 0.125f * Bq * Bk;
        }
    }
}

// ---------------- unified Q + gathered-KV projection GEMM (r11, unchanged) ----------------
__global__ __launch_bounds__(512, 2) void gemmU(const bf16* __restrict__ xb,
                                                const bf16* __restrict__ wqkv,
                                                bf16* __restrict__ tmpq,
                                                bf16* __restrict__ tmpkv) {
    extern __shared__ char lds[];
    const int wgid = xcd_remap(blockIdx.x, gridDim.x);   // 1197

    const int tid = threadIdx.x, lane = tid & 63, w = tid >> 6;
    const int li = lane & 15, lg = lane >> 4;
    const int wr = w >> 2, wc = w & 3;
    const int lr  = lane >> 3;
    const int lsw = ((lane & 7) ^ lr) << 3;

    const bool isQ = wgid < 591;
    int bm, bn, Mv, ldc;
    const bf16* Bb;
    bf16* C;
    if (isQ) { bm = wgid / 3;        bn = wgid % 3;        Mv = MXP;  ldc = 768;
               Bb = wqkv + (size_t)bn * 256 * 768;               C = tmpq; }
    else     { int t = wgid - 591;   bm = t / 6; bn = t % 6; Mv = MKVP; ldc = 1536;
               Bb = wqkv + (size_t)(768 + bn * 256) * 768;       C = tmpkv; }

    const bf16* abase[4];
    const bf16* bbase[4];
    #pragma unroll
    for (int h_ = 0; h_ < 4; ++h_) {
        int gr = bm * 256 + h_ * 64 + w * 8 + lr;
        size_t orig;
        if (isQ) {
            if (gr > MXP - 1) gr = MXP - 1;
            orig = (size_t)gr;
        } else {
            if (gr > MKV - 1) gr = MKV - 1;
            const unsigned b = (unsigned)gr / 3201u;
            const unsigned p = (unsigned)gr % 3201u;
            if (p == 0) orig = (size_t)b * NTOK;
            else {
                const unsigned q  = p - 1;
                const unsigned t2 = q / 400u, rem = q % 400u;
                const unsigned hi = rem / 20u, wi = rem % 20u;
                const int ih = 4 * (int)((hi + 1) / 3) + (int)((hi + 1) % 3) - 1;
                const int iw = 4 * (int)((wi + 1) / 3) + (int)((wi + 1) % 3) - 1;
                orig = (size_t)b * NTOK + 1 + ((size_t)t2 * HH + ih) * WW + iw;
            }
        }
        abase[h_] = xb + orig * 768 + lsw;
        bbase[h_] = Bb + (size_t)(h_ * 64 + w * 8 + lr) * 768 + lsw;
    }

    const int sw_  = (li & 7) << 4;
    const int swc0 = (lg * 16) ^ sw_;
    const int swc1 = (64 | (lg * 16)) ^ sw_;

#define STAGE_AH(Tt, a) do {                                                         \
        char* d_ = lds + ((Tt) & 1) * 65536;                                         \
        glds16(abase[2*(a)]   + (size_t)(Tt) * 64, d_ + ((2*(a))   * 64 + w * 8) * 128); \
        glds16(abase[2*(a)+1] + (size_t)(Tt) * 64, d_ + ((2*(a)+1) * 64 + w * 8) * 128); \
    } while (0)
#define STAGE_BH(Tt, b) do {                                                         \
        char* d_ = lds + ((Tt) & 1) * 65536 + 32768;                                 \
        glds16(bbase[2*(b)]   + (size_t)(Tt) * 64, d_ + ((2*(b))   * 64 + w * 8) * 128); \
        glds16(bbase[2*(b)+1] + (size_t)(Tt) * 64, d_ + ((2*(b)+1) * 64 + w * 8) * 128); \
    } while (0)

    f32x4 acc[8][4] = {};
    bf16x8 aF[4][2], bF0[2][2], bF1[2][2];

#define READ_A(mh)                                                                   \
    _Pragma("unroll") for (int mf = 0; mf < 4; ++mf) {                               \
        const char* p_ = bufA + (size_t)(wr * 128 + (mh) * 64 + mf * 16 + li) * 128; \
        aF[mf][0] = *(const bf16x8*)(p_ + swc0);                                     \
        aF[mf][1] = *(const bf16x8*)(p_ + swc1); }
#define READ_B(nh, BF)                                                               \
    _Pragma("unroll") for (int nf = 0; nf < 2; ++nf) {                               \
        const char* p_ = bufB + (size_t)(wc * 64 + (nh) * 32 + nf * 16 + li) * 128;  \
        BF[nf][0] = *(const bf16x8*)(p_ + swc0);                                     \
        BF[nf][1] = *(const bf16x8*)(p_ + swc1); }
#define MFMA_PH(mh, nh, BF)                                                          \
    _Pragma("unroll") for (int mf = 0; mf < 4; ++mf)                                 \
    _Pragma("unroll") for (int nf = 0; nf < 2; ++nf) {                               \
        acc[(mh)*4+mf][(nh)*2+nf] = MFMA16(aF[mf][0], BF[nf][0], acc[(mh)*4+mf][(nh)*2+nf]); \
        acc[(mh)*4+mf][(nh)*2+nf] = MFMA16(aF[mf][1], BF[nf][1], acc[(mh)*4+mf][(nh)*2+nf]); }

    STAGE_BH(0, 0); STAGE_BH(0, 1); STAGE_AH(0, 0); STAGE_AH(0, 1);
    STAGE_BH(1, 0); STAGE_BH(1, 1); STAGE_AH(1, 0);
    asm volatile("s_waitcnt vmcnt(6)" ::: "memory");
    __builtin_amdgcn_s_barrier();

    #pragma unroll
    for (int k = 0; k < 12; ++k) {
        const char* bufA = lds + (k & 1) * 65536;
        const char* bufB = bufA + 32768;
        READ_A(0); READ_B(0, bF0);
        if (k < 11) STAGE_AH(k + 1, 1);
        __builtin_amdgcn_s_barrier();
        asm volatile("s_waitcnt lgkmcnt(0)" ::: "memory");
        __builtin_amdgcn_s_setprio(1);
        MFMA_PH(0, 0, bF0);
        __builtin_amdgcn_s_setprio(0);
        __builtin_amdgcn_s_barrier();
        READ_B(1, bF1);
        __builtin_amdgcn_s_barrier();
        asm volatile("s_waitcnt lgkmcnt(0)" ::: "memory");
        __builtin_amdgcn_s_setprio(1);
        MFMA_PH(0, 1, bF1);
        __builtin_amdgcn_s_setprio(0);
        __builtin_amdgcn_s_barrier();
        READ_A(1);
        if (k < 10) { STAGE_BH(k + 2, 0); STAGE_BH(k + 2, 1); }
        __builtin_amdgcn_s_barrier();
        asm volatile("s_waitcnt lgkmcnt(0)" ::: "memory");
        __builtin_amdgcn_s_setprio(1);
        MFMA_PH(1, 0, bF0);
        __builtin_amdgcn_s_setprio(0);
        __builtin_amdgcn_s_barrier();
        if (k < 10) STAGE_AH(k + 2, 0);
        __builtin_amdgcn_s_barrier();
        __builtin_amdgcn_s_setprio(1);
        MFMA_PH(1, 1, bF1);
        __builtin_amdgcn_s_setprio(0);
        if (k < 10)       asm volatile("s_waitcnt vmcnt(6)" ::: "memory");
        else if (k == 10) asm volatile("s_waitcnt vmcnt(0)" ::: "memory");
        __builtin_amdgcn_s_barrier();
    }
#undef STAGE_AH
#undef STAGE_BH
#undef READ_A
#undef READ_B
#undef MFMA_PH

    #pragma unroll
    for (int mf = 0; mf < 8; ++mf) {
        const int row0 = bm * 256 + wr * 128 + mf * 16 + lg * 4;
        #pragma unroll
        for (int nf = 0; nf < 4; ++nf) {
            const int col = bn * 256 + wc * 64 + nf * 16 + li;
            #pragma unroll
            for (int r = 0; r < 4; ++r) {
                const int row = row0 + r;
                if (row < Mv)
                    C[(size_t)row * ldc + col] = (bf16)acc[mf][nf][r];
            }
        }
    }
}

// ---------------- final projection GEMM: 256x128 tile (r9, unchanged) ----------------
__global__ __launch_bounds__(512, 2) void gemmF(const bf16* __restrict__ A,
                                                const bf16* __restrict__ Bw,
                                                float* __restrict__ Cptr,
                                                const float* __restrict__ bias,
                                                int nbn, int Mvalid, int Aclamp) {
    extern __shared__ char lds[];
    const int wgid = xcd_remap(blockIdx.x, gridDim.x);
    const int bm = wgid / nbn, bn = wgid % nbn;

    const int tid = threadIdx.x, lane = tid & 63, w = tid >> 6;
    const int li = lane & 15, lg = lane >> 4;
    const int wr = w >> 2, wc = w & 3;
    const int lr  = lane >> 3;
    const int lsw = ((lane & 7) ^ lr) << 3;
    const bf16* Agp = A  + (size_t)bm * 256 * 768;
    const bf16* Bgp = Bw + (size_t)bn * 128 * 768;
    const int clampA = Aclamp - bm * 256;

    const int sw_  = (li & 7) << 4;
    const int swc0 = (lg * 16) ^ sw_;
    const int swc1 = (64 | (lg * 16)) ^ sw_;

#define STAGE_T(Tt, buf) do {                                                        \
        char* d_ = lds + (buf) * 49152;                                              \
        _Pragma("unroll")                                                            \
        for (int h_ = 0; h_ < 4; ++h_) {                                             \
            const int r0_ = h_ * 64 + w * 8;                                         \
            int gr_ = r0_ + lr; if (gr_ >= clampA) gr_ = clampA - 1;                 \
            glds16(Agp + (size_t)gr_ * 768 + (Tt) * 64 + lsw, d_ + r0_ * 128);       \
        }                                                                            \
        _Pragma("unroll")                                                            \
        for (int h_ = 0; h_ < 2; ++h_) {                                             \
            const int r0_ = h_ * 64 + w * 8;                                         \
            glds16(Bgp + (size_t)(r0_ + lr) * 768 + (Tt) * 64 + lsw,                 \
                   d_ + 32768 + r0_ * 128);                                          \
        } } while (0)

    f32x4 acc[8][2] = {};
    bf16x8 aF[8], bF[2];

#define READ_K(sw)                                                                   \
    _Pragma("unroll") for (int mf = 0; mf < 8; ++mf)                                 \
        aF[mf] = *(const bf16x8*)(bufA + (size_t)(wr * 128 + mf * 16 + li) * 128 + (sw)); \
    _Pragma("unroll") for (int nf = 0; nf < 2; ++nf)                                 \
        bF[nf] = *(const bf16x8*)(bufB + (size_t)(wc * 32 + nf * 16 + li) * 128 + (sw));

#define MFMA_K()                                                                     \
    _Pragma("unroll") for (int mf = 0; mf < 8; ++mf)                                 \
    _Pragma("unroll") for (int nf = 0; nf < 2; ++nf)                                 \
        acc[mf][nf] = MFMA16(aF[mf], bF[nf], acc[mf][nf]);

    STAGE_T(0, 0);
    STAGE_T(1, 1);
    asm volatile("s_waitcnt vmcnt(6)" ::: "memory");
    __builtin_amdgcn_s_barrier();
    __builtin_amdgcn_sched_barrier(0);

    #pragma unroll
    for (int T = 0; T < 12; ++T) {
        const char* bufA = lds + (T & 1) * 49152;
        const char* bufB = bufA + 32768;
        if (T >= 1 && T < 11) STAGE_T(T + 1, (T + 1) & 1);
        READ_K(swc0);
        __builtin_amdgcn_s_setprio(1);
        MFMA_K();
        __builtin_amdgcn_s_setprio(0);
        READ_K(swc1);
        __builtin_amdgcn_s_setprio(1);
        MFMA_K();
        __builtin_amdgcn_s_setprio(0);
        asm volatile("s_waitcnt lgkmcnt(0)" ::: "memory");
        if (T < 11) asm volatile("s_waitcnt vmcnt(0)" ::: "memory");
        __builtin_amdgcn_s_barrier();
        __builtin_amdgcn_sched_barrier(0);
    }
#undef STAGE_T
#undef READ_K
#undef MFMA_K

    #pragma unroll
    for (int mf = 0; mf < 8; ++mf) {
        const int row0 = bm * 256 + wr * 128 + mf * 16 + lg * 4;
        #pragma unroll
        for (int nf = 0; nf < 2; ++nf) {
            const int col = bn * 128 + wc * 32 + nf * 16 + li;
            #pragma unroll
            for (int r = 0; r < 4; ++r) {
                const int row = row0 + r;
                if (row < Mvalid)
                    Cptr[(size_t)row * 768 + col] = acc[mf][nf][r] + bias[col];
            }
        }
    }
}

// ---------------- pool_q LDS-slab: block = (b, oh, head), all 8 t x 14 ow ----------------
// Stages rows it=0..7 x ih in {2oh-1,2oh,2oh+1} x 28 iw x 64 ch into a padded
// slab [it*3+dh][28][72] (stride 144B kills bank aliasing), then 27-tap conv
// from LDS + LN per (token, head) with 8-lane-group shfl reduce.
__global__ __launch_bounds__(256) void pool_q_slab(const bf16* __restrict__ tmpq,
                                                   const float* __restrict__ wt,
                                                   const float* __restrict__ gamma,
                                                   const float* __restrict__ beta,
                                                   bf16* __restrict__ qn) {
    extern __shared__ char smem[];
    bf16*  slab = (bf16*)smem;               // [24][28][72] = 96768 B
    float* wl   = (float*)(smem + 96768);    // [27][64]     = 6912 B
    const int bid = blockIdx.x;              // 8b * 14oh * 12head = 1344
    const int head = bid % 12;
    int r = bid / 12;
    const int oh = r % 14;
    const int b  = r / 14;
    const int tid = threadIdx.x;

    for (int i = tid; i < 27 * 64; i += 256) wl[i] = wt[i];

    // stage: for each valid dh row-set, 8 it x 28 iw x 64ch = 1792 chunks of 16B
    const size_t gbase = ((size_t)b * NTOK + 1) * 768 + head * 64;
    #pragma unroll
    for (int dh = 0; dh < 3; ++dh) {
        const int ih = 2 * oh + dh - 1;
        if (ih < 0 || ih >= 28) continue;            // block-uniform
        #pragma unroll
        for (int pass = 0; pass < 7; ++pass) {
            const int c  = pass * 256 + tid;         // 0..1791
            const int it = c / 224;
            const int rem = c % 224;
            const int iw = rem >> 3, cg8 = rem & 7;
            u32x4 v = *(const u32x4*)(tmpq + gbase + (size_t)((it * 28 + ih) * 28 + iw) * 768 + cg8 * 8);
            *(u32x4*)&slab[((it * 3 + dh) * 28 + iw) * 72 + cg8 * 8] = v;
        }
    }
    __syncthreads();

    const int cg = tid & 7;
    #pragma unroll
    for (int pass = 0; pass < 4; ++pass) {
        const int item = pass * 32 + (tid >> 3);     // 0..111 valid (8t x 14ow)
        const bool ok = (item < 112);
        const int tL = ok ? item / 14 : 0;
        const int ow = ok ? item % 14 : 0;
        float acc[8] = {};
        #pragma unroll
        for (int dt = 0; dt < 3; ++dt) {
            const int it = tL + dt - 1;
            if (it < 0 || it >= 8) continue;         // per-item (predicated)
            #pragma unroll
            for (int dh = 0; dh < 3; ++dh) {
                const int ih = 2 * oh + dh - 1;
                if (ih < 0 || ih >= 28) continue;    // uniform
                #pragma unroll
                for (int dw = 0; dw < 3; ++dw) {
                    const int iw = 2 * ow + dw - 1;
                    if (iw < 0 || iw >= 28) continue;
                    bf16x8 v = *(const bf16x8*)&slab[((it * 3 + dh) * 28 + iw) * 72 + cg * 8];
                    const float* wp = wl + ((dt * 3 + dh) * 3 + dw) * 64 + cg * 8;
                    f32x4 w0 = *(const f32x4*)wp, w1 = *(const f32x4*)(wp + 4);
                    #pragma unroll
                    for (int e = 0; e < 4; ++e) {
                        acc[e]     += w0[e] * (float)v[e];
                        acc[4 + e] += w1[e] * (float)v[4 + e];
                    }
                }
            }
        }
        float s = 0;
        #pragma unroll
        for (int e = 0; e < 8; ++e) s += acc[e];
        s += __shfl_xor(s, 1); s += __shfl_xor(s, 2); s += __shfl_xor(s, 4);
        const float mu = s * 0.015625f;
        float v2 = 0;
        #pragma unroll
        for (int e = 0; e < 8; ++e) { float d = acc[e] - mu; v2 += d * d; }
        v2 += __shfl_xor(v2, 1); v2 += __shfl_xor(v2, 2); v2 += __shfl_xor(v2, 4);
        const float rs = rsqrtf(v2 * 0.015625f + 1e-5f);
        if (ok) {
            const int c0 = cg * 8;
            f32x4 g0 = *(const f32x4*)(gamma + c0), g1 = *(const f32x4*)(gamma + c0 + 4);
            f32x4 b0 = *(const f32x4*)(beta + c0),  b1 = *(const f32x4*)(beta + c0 + 4);
            bf16x8 o;
            #pragma unroll
            for (int e = 0; e < 4; ++e) {
                o[e]     = (bf16)(((acc[e]     - mu) * rs * g0[e] + b0[e]) * 0.125f);
                o[4 + e] = (bf16)(((acc[4 + e] - mu) * rs * g1[e] + b1[e]) * 0.125f);
            }
            const int p = 1 + (tL * 14 + oh) * 14 + ow;
            *(bf16x8*)(qn + ((size_t)(b * 12 + head) * NQP + p) * HD + c0) = o;
        }
    }
}

// ---------------- merged pool_k + pool_v (compact src) + q-cls/pad ----------------
__global__ __launch_bounds__(256) void pool_kv(const bf16* __restrict__ tmpkv,
                                               const bf16* __restrict__ tmpq,
                                               const float* __restrict__ wt,
                                               const float* __restrict__ gk, const float* __restrict__ bk,
                                               const float* __restrict__ gv, const float* __restrict__ bv,
                                               const float* __restrict__ gq, const float* __restrict__ bq,
                                               bf16* __restrict__ kn, bf16* __restrict__ vnb,
                                               bf16* __restrict__ qn) {
    const int w = threadIdx.x >> 6, lane = threadIdx.x & 63;
    const int gw = xcd_remap(blockIdx.x, gridDim.x) * 4 + w;   // 0..11039
    const int owg = lane >> 3, cg = lane & 7, c = cg * 8;

    if (gw >= 10944) {   // q-cls + qn zero pad: bh = gw - 10944
        const int bh = gw - 10944;
        if (bh >= 96) return;
        const int b = bh / NH, head = bh % NH;
        if (owg == 0) {
            const bf16* src = tmpq + ((size_t)b * NTOK) * CC + head * HD + c;
            bf16x8 v = *(const bf16x8*)src;
            float a[8];
            #pragma unroll
            for (int e = 0; e < 8; ++e) a[e] = (float)v[e];
            float s = 0;
            #pragma unroll
            for (int e = 0; e < 8; ++e) s += a[e];
            s += __shfl_xor(s, 1); s += __shfl_xor(s, 2); s += __shfl_xor(s, 4);
            const float mu = s * 0.015625f;
            float v2 = 0;
            #pragma unroll
            for (int e = 0; e < 8; ++e) { float d = a[e] - mu; v2 += d * d; }
            v2 += __shfl_xor(v2, 1); v2 += __shfl_xor(v2, 2); v2 += __shfl_xor(v2, 4);
            const float rs = rsqrtf(v2 * 0.015625f + 1e-5f);
            f32x4 g0 = *(const f32x4*)(gq + c), g1 = *(const f32x4*)(gq + c + 4);
            f32x4 b0 = *(const f32x4*)(bq + c), b1 = *(const f32x4*)(bq + c + 4);
            bf16x8 o;
            #pragma unroll
            for (int e = 0; e < 4; ++e) {
                o[e]     = (bf16)(((a[e]     - mu) * rs * g0[e] + b0[e]) * 0.125f);
                o[4 + e] = (bf16)(((a[4 + e] - mu) * rs * g1[e] + b1[e]) * 0.125f);
            }
            *(bf16x8*)(qn + ((size_t)bh * NQP) * HD + c) = o;
        } else {
            bf16x8 z = {};
            for (int p = NQ + owg - 1; p < NQP; p += 7)
                *(bf16x8*)(qn + ((size_t)bh * NQP + p) * HD + c) = z;
        }
        return;
    }

    const int set = gw / 5472;            // 0 = k, 1 = v
    const int gw2 = gw % 5472;
    constexpr int TASKS = TT * 7 + 1;     // 57
    const int bh = gw2 / TASKS, task = gw2 % TASKS;
    const int b = bh / NH, head = bh % NH;
    const bf16* P = tmpkv + set * 768;
    const float* wtp = wt + 1728 + set * 1728;
    const float* gamma = set ? gv : gk;
    const float* beta  = set ? bv : bk;
    bf16* outp = set ? vnb : kn;
    const size_t pbase = (size_t)b * CTOK * 1536 + head * HD + c;

    if (task == TASKS - 1) {
        if (owg == 0) {
            bf16x8 v = *(const bf16x8*)(P + pbase);
            float a[8];
            #pragma unroll
            for (int e = 0; e < 8; ++e) a[e] = (float)v[e];
            float s = 0;
            #pragma unroll
            for (int e = 0; e < 8; ++e) s += a[e];
            s += __shfl_xor(s, 1); s += __shfl_xor(s, 2); s += __shfl_xor(s, 4);
            const float mu = s * 0.015625f;
            float v2 = 0;
            #pragma unroll
            for (int e = 0; e < 8; ++e) { float d = a[e] - mu; v2 += d * d; }
            v2 += __shfl_xor(v2, 1); v2 += __shfl_xor(v2, 2); v2 += __shfl_xor(v2, 4);
            const float rs = rsqrtf(v2 * 0.015625f + 1e-5f);
            f32x4 g0 = *(const f32x4*)(gamma + c), g1 = *(const f32x4*)(gamma + c + 4);
            f32x4 b0 = *(const f32x4*)(beta + c),  b1 = *(const f32x4*)(beta + c + 4);
            bf16x8 o;
            #pragma unroll
            for (int e = 0; e < 4; ++e) {
                o[e]     = (bf16)((a[e]     - mu) * rs * g0[e] + b0[e]);
                o[4 + e] = (bf16)((a[4 + e] - mu) * rs * g1[e] + b1[e]);
            }
            *(bf16x8*)(outp + ((size_t)bh * NKP) * HD + c) = o;
        } else {
            bf16x8 z = {};
            for (int p = NK + owg - 1; p < NKP; p += 7)
                *(bf16x8*)(outp + ((size_t)bh * NKP + p) * HD + c) = z;
        }
        return;
    }

    const int t  = task / 7;
    const int oh = task % 7;
    const int ow = owg;
    const bool active = (ow < 7);

    float acc[8] = {};
    #pragma unroll
    for (int dt = 0; dt < 3; ++dt) {
        const int it = t + dt - 1;
        if (it < 0 || it >= TT) continue;
        #pragma unroll
        for (int dh = 0; dh < 3; ++dh) {
            const int hi = 3 * oh + dh - 1;
            if (hi < 0) continue;
            const int rowh = 1 + it * 400 + hi * 20;
            #pragma unroll
            for (int dw = 0; dw < 3; ++dw) {
                const int wi = 3 * ow + dw - 1;
                if (active && wi >= 0) {
                    bf16x8 v = *(const bf16x8*)(P + pbase + (size_t)(rowh + wi) * 1536);
                    const float* wp = wtp + ((dt * 3 + dh) * 3 + dw) * 64 + c;
                    f32x4 w0 = *(const f32x4*)wp, w1 = *(const f32x4*)(wp + 4);
                    #pragma unroll
                    for (int e = 0; e < 4; ++e) {
                        acc[e]     += w0[e] * (float)v[e];
                        acc[4 + e] += w1[e] * (float)v[4 + e];
                    }
                }
            }
        }
    }
    float s = 0;
    #pragma unroll
    for (int e = 0; e < 8; ++e) s += acc[e];
    s += __shfl_xor(s, 1); s += __shfl_xor(s, 2); s += __shfl_xor(s, 4);
    const float mu = s * 0.015625f;
    float v2 = 0;
    #pragma unroll
    for (int e = 0; e < 8; ++e) { float d = acc[e] - mu; v2 += d * d; }
    v2 += __shfl_xor(v2, 1); v2 += __shfl_xor(v2, 2); v2 += __shfl_xor(v2, 4);
    const float rs = rsqrtf(v2 * 0.015625f + 1e-5f);
    if (active) {
        f32x4 g0 = *(const f32x4*)(gamma + c), g1 = *(const f32x4*)(gamma + c + 4);
        f32x4 b0 = *(const f32x4*)(beta + c),  b1 = *(const f32x4*)(beta + c + 4);
        bf16x8 o;
        #pragma unroll
        for (int e = 0; e < 4; ++e) {
            o[e]     = (bf16)((acc[e]     - mu) * rs * g0[e] + b0[e]);
            o[4 + e] = (bf16)((acc[4 + e] - mu) * rs * g1[e] + b1[e]);
        }
        const int p = 1 + (t * 7 + oh) * 7 + ow;
        *(bf16x8*)(outp + ((size_t)bh * NKP + p) * HD + c) = o;
    }
}

// ---------------- flash attention, fixed-max softmax (r10, unchanged) ----------------
__global__ __launch_bounds__(256) void attn_kernel(const bf16* __restrict__ qn,
                                                   const bf16* __restrict__ kn,
                                                   const bf16* __restrict__ vn,
                                                   bf16* __restrict__ ob,
                                                   const float* __restrict__ Mptr) {
    __shared__ bf16 Kl[2][32][72];
    __shared__ bf16 Vt[2][64][40];
    __shared__ bf16 Pl[4][16][40];

    const int tid = threadIdx.x, l = tid & 63, w = tid >> 6;
    const int li = l & 15, lg = l >> 4;
    const int wgid = xcd_remap(blockIdx.x, gridDim.x);
    const int bh = wgid / 25;
    const int b = bh / NH, head = bh % NH;
    const int qbase = (wgid % 25) * 64 + w * 16;
    const float M = Mptr[0];

    const bf16* qp = qn + ((size_t)bh * NQP + qbase + li) * HD + lg * 8;
    const bf16x8 aq0 = *(const bf16x8*)qp;
    const bf16x8 aq1 = *(const bf16x8*)(qp + 32);

    const int srow = tid >> 3, scol = (tid & 7) * 8;
    const int sj = tid & 31, sd8 = tid >> 5;
    const bf16* kbase = kn + (size_t)bh * NKP * HD;
    const bf16* vbase = vn + (size_t)bh * NKP * HD;

    u32x4 kv = *(const u32x4*)(kbase + srow * HD + scol);
    u32x4 vv = *(const u32x4*)(vbase + sj * HD + sd8 * 8);
    *(u32x4*)&Kl[0][srow][scol] = kv;
    {
        bf16x8 t = __builtin_bit_cast(bf16x8, vv);
        #pragma unroll
        for (int e = 0; e < 8; ++e) Vt[0][sd8 * 8 + e][sj] = t[e];
    }

    f32x4 oacc[4] = {};
    float lpart[4] = {0.f, 0.f, 0.f, 0.f};

    for (int kt = 0; kt < 13; ++kt) {
        const int cur = kt & 1;
        if (kt < 12) {
            kv = *(const u32x4*)(kbase + (kt + 1) * 32 * HD + srow * HD + scol);
            vv = *(const u32x4*)(vbase + (kt + 1) * 32 * HD + sj * HD + sd8 * 8);
        }
        __syncthreads();

        f32x4 c0 = {}, c1 = {};
        const bf16x8 b00 = *(const bf16x8*)&Kl[cur][li][lg * 8];
        const bf16x8 b01 = *(const bf16x8*)&Kl[cur][li][32 + lg * 8];
        const bf16x8 b10 = *(const bf16x8*)&Kl[cur][16 + li][lg * 8];
        const bf16x8 b11 = *(const bf16x8*)&Kl[cur][16 + li][32 + lg * 8];
        __builtin_amdgcn_s_setprio(1);
        c0 = MFMA16(aq0, b00, c0); c0 = MFMA16(aq1, b01, c0);
        c1 = MFMA16(aq0, b10, c1); c1 = MFMA16(aq1, b11, c1);
        __builtin_amdgcn_s_setprio(0);

        float p0[4], p1[4];
        #pragma unroll
        for (int r = 0; r < 4; ++r) {
            p0[r] = __expf(c0[r] - M);
            p1[r] = __expf(c1[r] - M);
        }
        if (kt == 12) {
            const bool m0 = (384 + li) >= NK;
            #pragma unroll
            for (int r = 0; r < 4; ++r) { if (m0) p0[r] = 0.f; p1[r] = 0.f; }
        }
        #pragma unroll
        for (int r = 0; r < 4; ++r) {
            lpart[r] += p0[r] + p1[r];
            Pl[w][lg * 4 + r][li]      = (bf16)p0[r];
            Pl[w][lg * 4 + r][16 + li] = (bf16)p1[r];
        }
        const bf16x8 ap = *(const bf16x8*)&Pl[w][li][lg * 8];
        __builtin_amdgcn_s_setprio(1);
        #pragma unroll
        for (int dg = 0; dg < 4; ++dg) {
            const bf16x8 bv = *(const bf16x8*)&Vt[cur][dg * 16 + li][lg * 8];
            oacc[dg] = MFMA16(ap, bv, oacc[dg]);
        }
        __builtin_amdgcn_s_setprio(0);

        if (kt < 12) {
            const int nxt = cur ^ 1;
            *(u32x4*)&Kl[nxt][srow][scol] = kv;
            bf16x8 t = __builtin_bit_cast(bf16x8, vv);
            #pragma unroll
            for (int e = 0; e < 8; ++e) Vt[nxt][sd8 * 8 + e][sj] = t[e];
        }
    }
    #pragma unroll
    for (int r = 0; r < 4; ++r) {
        float lsum = lpart[r];
        lsum += __shfl_xor(lsum, 1);
        lsum += __shfl_xor(lsum, 2);
        lsum += __shfl_xor(lsum, 4);
        lsum += __shfl_xor(lsum, 8);
        const int q = qbase + lg * 4 + r;
        if (q < NQ) {
            const float inv = 1.f / lsum;
            const size_t off = ((size_t)(b * NQ + q)) * CC + head * HD;
            #pragma unroll
            for (int dg = 0; dg < 4; ++dg)
                ob[off + dg * 16 + li] = (bf16)(oacc[dg][r] * inv);
        }
    }
}

// ---------------- launcher ----------------
extern "C" void kernel_launch(void* const* d_in, const int* in_sizes, int n_in,
                              void* d_out, int out_size, void* d_ws, size_t ws_size,
                              hipStream_t stream) {
    const float* x     = (const float*)d_in[0];
    const float* Wq    = (const float*)d_in[1];
    const float* Wk    = (const float*)d_in[2];
    const float* Wv    = (const float*)d_in[3];
    const float* Wproj = (const float*)d_in[4];
    const float* bproj = (const float*)d_in[5];
    const float* pqw   = (const float*)d_in[6];
    const float* pkw   = (const float*)d_in[7];
    const float* pvw   = (const float*)d_in[8];
    const float* gq    = (const float*)d_in[9];
    const float* bq    = (const float*)d_in[10];
    const float* gk    = (const float*)d_in[11];
    const float* bk    = (const float*)d_in[12];
    const float* gv    = (const float*)d_in[13];
    const float* bv    = (const float*)d_in[14];

    if (ws_size < 364000000ULL) return;
    char* ws = (char*)d_ws;
    bf16* xb    = (bf16*)(ws);               // [50304][768]
    bf16* wqkv  = (bf16*)(ws + 77266944);    // [2304][768] + wpb contiguous
    bf16* wpb   = (bf16*)(ws + 80805888);    // [768][768]
    bf16* tmpq  = (bf16*)(ws + 81985536);    // [50304][768]
    bf16* tmpkv = (bf16*)(ws + 159252480);   // [25856][1536]
    bf16* qn    = (bf16*)(ws + 238682112);   // [96][1600][64]
    bf16* kn    = (bf16*)(ws + 258342912);   // [96][416][64]
    bf16* vnb   = (bf16*)(ws + 263454720);   // [96][416][64]
    bf16* ob    = (bf16*)(ws + 268566528);   // [12672][768]
    float* wt   = (float*)(ws + 288030720);  // [3][27][64] f32
    float* Mb   = (float*)(ws + 288051456);  // [1]

    (void)hipFuncSetAttribute((const void*)gemmU,
                              hipFuncAttributeMaxDynamicSharedMemorySize, 131072);
    (void)hipFuncSetAttribute((const void*)gemmF,
                              hipFuncAttributeMaxDynamicSharedMemorySize, 98304);
    (void)hipFuncSetAttribute((const void*)pool_q_slab,
                              hipFuncAttributeMaxDynamicSharedMemorySize, 103680);

    cast_f32_bf16<<<4096, 256, 0, stream>>>(x, xb, MX * CC, MXP * CC);
    prep<<<2326, 256, 0, stream>>>(Wq, Wk, Wv, Wproj, pqw, pkw, pvw,
                                   gq, bq, gk, bk, wqkv, wt, Mb);

    gemmU<<<1197, 512, 131072, stream>>>(xb, wqkv, tmpq, tmpkv);

    pool_q_slab<<<1344, 256, 103680, stream>>>(tmpq, wt, gq, bq, qn);
    pool_kv<<<2760, 256, 0, stream>>>(tmpkv, tmpq, wt, gk, bk, gv, bv, gq, bq, kn, vnb, qn);

    attn_kernel<<<2400, 256, 0, stream>>>(qn, kn, vnb, ob, Mb);

    gemmF<<<50 * 6, 512, 98304, stream>>>(ob, wpb, (float*)d_out, bproj, 6, MO, MOP);
}

// Round 13
// 335.470 us; speedup vs baseline: 1.1130x; 1.1130x over previous
//
#include <hip/hip_runtime.h>

using bf16   = __bf16;
using bf16x4 = __attribute__((ext_vector_type(4))) __bf16;
using bf16x8 = __attribute__((ext_vector_type(8))) __bf16;
using f32x4  = __attribute__((ext_vector_type(4))) float;
using u32x4  = __attribute__((ext_vector_type(4))) unsigned int;

#define MFMA16(a,b,c) __builtin_amdgcn_mfma_f32_16x16x32_bf16((a),(b),(c),0,0,0)

__device__ inline void glds16(const void* g, void* l) {
    __builtin_amdgcn_global_load_lds(
        (__attribute__((address_space(1))) void*)(const_cast<void*>(g)),
        (__attribute__((address_space(3))) void*)(l), 16, 0, 0);
}

// bijective XCD-chunked remap (m204)
__device__ inline int xcd_remap(int bid, int nwg) {
    const int xcd = bid & 7, loc = bid >> 3;
    const int q8 = nwg >> 3, r8 = nwg & 7;
    return (xcd < r8 ? xcd * (q8 + 1) : r8 * (q8 + 1) + (xcd - r8) * q8) + loc;
}

// ---------------- constants ----------------
constexpr int CB   = 8;
constexpr int NH   = 12;
constexpr int CC   = 768;
constexpr int HD   = 64;
constexpr int TT   = 8, HH = 28, WW = 28;
constexpr int NTOK = TT*HH*WW + 1;      // 6273
constexpr int MX   = CB*NTOK;           // 50184
constexpr int MXP  = 50304;
constexpr int NQ   = 1569, NQP = 1600;
constexpr int NK   = 393,  NKP = 416;
constexpr int MO   = CB*NQ;             // 12552
constexpr int MOP  = 12672;
constexpr int CTOK = 1 + TT*20*20;      // 3201
constexpr int MKV  = CB*CTOK;           // 25608
constexpr int MKVP = 25856;

// ---------------- merged prep: x-cast + weight cast + wt transpose + bound ----------------
__global__ __launch_bounds__(256) void prep_all(const float* __restrict__ x,
                                                const float* __restrict__ Wq, const float* __restrict__ Wk,
                                                const float* __restrict__ Wv, const float* __restrict__ Wp,
                                                const float* __restrict__ pqw, const float* __restrict__ pkw,
                                                const float* __restrict__ pvw,
                                                const float* __restrict__ gq, const float* __restrict__ bq,
                                                const float* __restrict__ gk, const float* __restrict__ bk,
                                                bf16* __restrict__ xb, bf16* __restrict__ wdst,
                                                float* __restrict__ wt, float* __restrict__ Mb) {
    constexpr int WSZ = 589824;
    const int bid = blockIdx.x, tid = threadIdx.x;
    if (bid < 4096) {
        const int nvalid = MX * CC, ntotal = MXP * CC;
        int i = (bid * 256 + tid) * 4;
        const int stride = 4096 * 256 * 4;
        for (; i < ntotal; i += stride) {
            bf16x4 o;
            if (i + 3 < nvalid) {
                f32x4 v = *(const f32x4*)(x + i);
                #pragma unroll
                for (int e = 0; e < 4; ++e) o[e] = (bf16)v[e];
            } else {
                #pragma unroll
                for (int e = 0; e < 4; ++e) {
                    int k = i + e;
                    o[e] = (bf16)((k < nvalid) ? x[k] : 0.f);
                }
            }
            *(bf16x4*)(xb + i) = o;
        }
    } else if (bid < 6400) {
        int i = ((bid - 4096) * 256 + tid) * 4;
        const int setn = i / WSZ, j = i % WSZ;
        const float* src = (setn == 0) ? Wq : (setn == 1) ? Wk : (setn == 2) ? Wv : Wp;
        f32x4 v = *(const f32x4*)(src + j);
        bf16x4 o;
        #pragma unroll
        for (int e = 0; e < 4; ++e) o[e] = (bf16)v[e];
        *(bf16x4*)(wdst + i) = o;
    } else if (bid < 6421) {
        int i = (bid - 6400) * 256 + tid;
        if (i < 3 * 1728) {
            int setn = i / 1728, j = i % 1728;
            const float* src = (setn == 0) ? pqw : (setn == 1) ? pkw : pvw;
            int tap = j / 64, c = j % 64;
            wt[i] = src[c * 27 + tap];
        }
    } else if (tid < 64) {
        const int c = tid;
        float mgq = fabsf(gq[c]), sbq = bq[c] * bq[c];
        float mgk = fabsf(gk[c]), sbk = bk[c] * bk[c];
        #pragma unroll
        for (int m = 1; m < 64; m <<= 1) {
            mgq = fmaxf(mgq, __shfl_xor(mgq, m)); sbq += __shfl_xor(sbq, m);
            mgk = fmaxf(mgk, __shfl_xor(mgk, m)); sbk += __shfl_xor(sbk, m);
        }
        if (c == 0) {
            const float Bq = 8.f * mgq + sqrtf(sbq);
            const float Bk = 8.f * mgk + sqrtf(sbk);
            Mb[0] = 0.125f * Bq * Bk;
        }
    }
}

// ---------------- unified Q + gathered-KV projection GEMM (r10 one-barrier, 138.5 us) ----------------
__global__ __launch_bounds__(512, 2) void gemmU(const bf16* __restrict__ xb,
                                                const bf16* __restrict__ wqkv,
                                                bf16* __restrict__ tmpq,
                                                bf16* __restrict__ tmpkv) {
    extern __shared__ char lds[];
    const int wgid = xcd_remap(blockIdx.x, gridDim.x);   // 1197

    const int tid = threadIdx.x, lane = tid & 63, w = tid >> 6;
    const int li = lane & 15, lg = lane >> 4;
    const int wr = w >> 2, wc = w & 3;
    const int lr  = lane >> 3;
    const int lsw = ((lane & 7) ^ lr) << 3;

    const bool isQ = wgid < 591;
    int bm, bn, Mv, ldc;
    const bf16* Bb;
    bf16* C;
    if (isQ) { bm = wgid / 3;        bn = wgid % 3;        Mv = MXP;  ldc = 768;
               Bb = wqkv + (size_t)bn * 256 * 768;               C = tmpq; }
    else     { int t = wgid - 591;   bm = t / 6; bn = t % 6; Mv = MKVP; ldc = 1536;
               Bb = wqkv + (size_t)(768 + bn * 256) * 768;       C = tmpkv; }

    const bf16* abase[4];
    const bf16* bbase[4];
    #pragma unroll
    for (int h_ = 0; h_ < 4; ++h_) {
        int gr = bm * 256 + h_ * 64 + w * 8 + lr;
        size_t orig;
        if (isQ) {
            if (gr > MXP - 1) gr = MXP - 1;
            orig = (size_t)gr;
        } else {
            if (gr > MKV - 1) gr = MKV - 1;
            const unsigned b = (unsigned)gr / 3201u;
            const unsigned p = (unsigned)gr % 3201u;
            if (p == 0) orig = (size_t)b * NTOK;
            else {
                const unsigned q  = p - 1;
                const unsigned t2 = q / 400u, rem = q % 400u;
                const unsigned hi = rem / 20u, wi = rem % 20u;
                const int ih = 4 * (int)((hi + 1) / 3) + (int)((hi + 1) % 3) - 1;
                const int iw = 4 * (int)((wi + 1) / 3) + (int)((wi + 1) % 3) - 1;
                orig = (size_t)b * NTOK + 1 + ((size_t)t2 * HH + ih) * WW + iw;
            }
        }
        abase[h_] = xb + orig * 768 + lsw;
        bbase[h_] = Bb + (size_t)(h_ * 64 + w * 8 + lr) * 768 + lsw;
    }

    const int sw_  = (li & 7) << 4;
    const int swc0 = (lg * 16) ^ sw_;
    const int swc1 = (64 | (lg * 16)) ^ sw_;

#define STAGE_T(Tt, buf) do {                                                        \
        char* d_ = lds + (buf) * 65536;                                              \
        _Pragma("unroll")                                                            \
        for (int h_ = 0; h_ < 4; ++h_)                                               \
            glds16(abase[h_] + (size_t)(Tt) * 64, d_ + (h_ * 64 + w * 8) * 128);     \
        _Pragma("unroll")                                                            \
        for (int h_ = 0; h_ < 4; ++h_)                                               \
            glds16(bbase[h_] + (size_t)(Tt) * 64, d_ + 32768 + (h_ * 64 + w * 8) * 128); \
    } while (0)

    f32x4 acc[8][4] = {};
    bf16x8 aF[8], bF[4];

#define READ_K(sw)                                                                   \
    _Pragma("unroll") for (int mf = 0; mf < 8; ++mf)                                 \
        aF[mf] = *(const bf16x8*)(bufA + (size_t)(wr * 128 + mf * 16 + li) * 128 + (sw)); \
    _Pragma("unroll") for (int nf = 0; nf < 4; ++nf)                                 \
        bF[nf] = *(const bf16x8*)(bufB + (size_t)(wc * 64 + nf * 16 + li) * 128 + (sw));

#define MFMA_K()                                                                     \
    _Pragma("unroll") for (int mf = 0; mf < 8; ++mf)                                 \
    _Pragma("unroll") for (int nf = 0; nf < 4; ++nf)                                 \
        acc[mf][nf] = MFMA16(aF[mf], bF[nf], acc[mf][nf]);

    STAGE_T(0, 0);
    STAGE_T(1, 1);
    asm volatile("s_waitcnt vmcnt(8)" ::: "memory");
    __builtin_amdgcn_s_barrier();
    __builtin_amdgcn_sched_barrier(0);

    #pragma unroll
    for (int T = 0; T < 12; ++T) {
        const char* bufA = lds + (T & 1) * 65536;
        const char* bufB = bufA + 32768;
        if (T >= 1 && T < 11) STAGE_T(T + 1, (T + 1) & 1);
        READ_K(swc0);
        __builtin_amdgcn_s_setprio(1);
        MFMA_K();
        __builtin_amdgcn_s_setprio(0);
        READ_K(swc1);
        __builtin_amdgcn_s_setprio(1);
        MFMA_K();
        __builtin_amdgcn_s_setprio(0);
        asm volatile("s_waitcnt lgkmcnt(0)" ::: "memory");
        if (T < 11) asm volatile("s_waitcnt vmcnt(0)" ::: "memory");
        __builtin_amdgcn_s_barrier();
        __builtin_amdgcn_sched_barrier(0);
    }
#undef STAGE_T
#undef READ_K
#undef MFMA_K

    #pragma unroll
    for (int mf = 0; mf < 8; ++mf) {
        const int row0 = bm * 256 + wr * 128 + mf * 16 + lg * 4;
        #pragma unroll
        for (int nf = 0; nf < 4; ++nf) {
            const int col = bn * 256 + wc * 64 + nf * 16 + li;
            #pragma unroll
            for (int r = 0; r < 4; ++r) {
                const int row = row0 + r;
                if (row < Mv)
                    C[(size_t)row * ldc + col] = (bf16)acc[mf][nf][r];
            }
        }
    }
}

// ---------------- final projection GEMM: 256x128 tile (r11, unchanged) ----------------
__global__ __launch_bounds__(512, 2) void gemmF(const bf16* __restrict__ A,
                                                const bf16* __restrict__ Bw,
                                                float* __restrict__ Cptr,
                                                const float* __restrict__ bias,
                                                int nbn, int Mvalid, int Aclamp) {
    extern __shared__ char lds[];
    const int wgid = xcd_remap(blockIdx.x, gridDim.x);
    const int bm = wgid / nbn, bn = wgid % nbn;

    const int tid = threadIdx.x, lane = tid & 63, w = tid >> 6;
    const int li = lane & 15, lg = lane >> 4;
    const int wr = w >> 2, wc = w & 3;
    const int lr  = lane >> 3;
    const int lsw = ((lane & 7) ^ lr) << 3;
    const bf16* Agp = A  + (size_t)bm * 256 * 768;
    const bf16* Bgp = Bw + (size_t)bn * 128 * 768;
    const int clampA = Aclamp - bm * 256;

    const int sw_  = (li & 7) << 4;
    const int swc0 = (lg * 16) ^ sw_;
    const int swc1 = (64 | (lg * 16)) ^ sw_;

#define STAGE_T(Tt, buf) do {                                                        \
        char* d_ = lds + (buf) * 49152;                                              \
        _Pragma("unroll")                                                            \
        for (int h_ = 0; h_ < 4; ++h_) {                                             \
            const int r0_ = h_ * 64 + w * 8;                                         \
            int gr_ = r0_ + lr; if (gr_ >= clampA) gr_ = clampA - 1;                 \
            glds16(Agp + (size_t)gr_ * 768 + (Tt) * 64 + lsw, d_ + r0_ * 128);       \
        }                                                                            \
        _Pragma("unroll")                                                            \
        for (int h_ = 0; h_ < 2; ++h_) {                                             \
            const int r0_ = h_ * 64 + w * 8;                                         \
            glds16(Bgp + (size_t)(r0_ + lr) * 768 + (Tt) * 64 + lsw,                 \
                   d_ + 32768 + r0_ * 128);                                          \
        } } while (0)

    f32x4 acc[8][2] = {};
    bf16x8 aF[8], bF[2];

#define READ_K(sw)                                                                   \
    _Pragma("unroll") for (int mf = 0; mf < 8; ++mf)                                 \
        aF[mf] = *(const bf16x8*)(bufA + (size_t)(wr * 128 + mf * 16 + li) * 128 + (sw)); \
    _Pragma("unroll") for (int nf = 0; nf < 2; ++nf)                                 \
        bF[nf] = *(const bf16x8*)(bufB + (size_t)(wc * 32 + nf * 16 + li) * 128 + (sw));

#define MFMA_K()                                                                     \
    _Pragma("unroll") for (int mf = 0; mf < 8; ++mf)                                 \
    _Pragma("unroll") for (int nf = 0; nf < 2; ++nf)                                 \
        acc[mf][nf] = MFMA16(aF[mf], bF[nf], acc[mf][nf]);

    STAGE_T(0, 0);
    STAGE_T(1, 1);
    asm volatile("s_waitcnt vmcnt(6)" ::: "memory");
    __builtin_amdgcn_s_barrier();
    __builtin_amdgcn_sched_barrier(0);

    #pragma unroll
    for (int T = 0; T < 12; ++T) {
        const char* bufA = lds + (T & 1) * 49152;
        const char* bufB = bufA + 32768;
        if (T >= 1 && T < 11) STAGE_T(T + 1, (T + 1) & 1);
        READ_K(swc0);
        __builtin_amdgcn_s_setprio(1);
        MFMA_K();
        __builtin_amdgcn_s_setprio(0);
        READ_K(swc1);
        __builtin_amdgcn_s_setprio(1);
        MFMA_K();
        __builtin_amdgcn_s_setprio(0);
        asm volatile("s_waitcnt lgkmcnt(0)" ::: "memory");
        if (T < 11) asm volatile("s_waitcnt vmcnt(0)" ::: "memory");
        __builtin_amdgcn_s_barrier();
        __builtin_amdgcn_sched_barrier(0);
    }
#undef STAGE_T
#undef READ_K
#undef MFMA_K

    #pragma unroll
    for (int mf = 0; mf < 8; ++mf) {
        const int row0 = bm * 256 + wr * 128 + mf * 16 + lg * 4;
        #pragma unroll
        for (int nf = 0; nf < 2; ++nf) {
            const int col = bn * 128 + wc * 32 + nf * 16 + li;
            #pragma unroll
            for (int r = 0; r < 4; ++r) {
                const int row = row0 + r;
                if (row < Mvalid)
                    Cptr[(size_t)row * 768 + col] = acc[mf][nf][r] + bias[col];
            }
        }
    }
}

// ---------------- pool body (exact r11 pool_norm2, parameterized by gw) ----------------
template<int S, int OH, int OW, int CH, int NP, int NPpad, int SRCSTRIDE, bool COMPACT>
__device__ __forceinline__ void pool_body(int gw, int lane,
                                          const bf16* __restrict__ P,
                                          const float* __restrict__ wt,
                                          const float* __restrict__ gamma,
                                          const float* __restrict__ beta,
                                          bf16* __restrict__ outp,
                                          float outScale) {
    constexpr int TASKS = TT * OH * CH + 1;
    const int bh = gw / TASKS, task = gw % TASKS;
    const int b = bh / NH, head = bh % NH;
    const int owg = lane >> 3, cg = lane & 7, c = cg * 8;
    const size_t rowbase = COMPACT ? (size_t)b * CTOK : (size_t)b * NTOK;
    const size_t pbase = rowbase * SRCSTRIDE + head * HD + c;

    if (task == TASKS - 1) {
        if (owg == 0) {
            bf16x8 v = *(const bf16x8*)(P + pbase);
            float a[8];
            #pragma unroll
            for (int e = 0; e < 8; ++e) a[e] = (float)v[e];
            float s = 0;
            #pragma unroll
            for (int e = 0; e < 8; ++e) s += a[e];
            s += __shfl_xor(s, 1); s += __shfl_xor(s, 2); s += __shfl_xor(s, 4);
            const float mu = s * 0.015625f;
            float v2 = 0;
            #pragma unroll
            for (int e = 0; e < 8; ++e) { float d = a[e] - mu; v2 += d * d; }
            v2 += __shfl_xor(v2, 1); v2 += __shfl_xor(v2, 2); v2 += __shfl_xor(v2, 4);
            const float rs = rsqrtf(v2 * 0.015625f + 1e-5f);
            f32x4 g0 = *(const f32x4*)(gamma + c), g1 = *(const f32x4*)(gamma + c + 4);
            f32x4 b0 = *(const f32x4*)(beta + c),  b1 = *(const f32x4*)(beta + c + 4);
            bf16x8 o;
            #pragma unroll
            for (int e = 0; e < 4; ++e) {
                o[e]     = (bf16)(((a[e]     - mu) * rs * g0[e] + b0[e]) * outScale);
                o[4 + e] = (bf16)(((a[4 + e] - mu) * rs * g1[e] + b1[e]) * outScale);
            }
            *(bf16x8*)(outp + ((size_t)bh * NPpad) * HD + c) = o;
        } else {
            bf16x8 z = {};
            for (int p = NP + owg - 1; p < NPpad; p += 7)
                *(bf16x8*)(outp + ((size_t)bh * NPpad + p) * HD + c) = z;
        }
        return;
    }

    const int t  = task / (OH * CH);
    const int r2 = task % (OH * CH);
    const int oh = r2 / CH;
    const int ow = (r2 % CH) * 8 + owg;
    const bool active = (ow < OW);

    float acc[8] = {0, 0, 0, 0, 0, 0, 0, 0};
    #pragma unroll
    for (int dt = 0; dt < 3; ++dt) {
        const int it = t + dt - 1;
        if (it < 0 || it >= TT) continue;
        #pragma unroll
        for (int dh = 0; dh < 3; ++dh) {
            int rowh;
            if constexpr (COMPACT) {
                const int hi = 3 * oh + dh - 1;
                if (hi < 0) continue;
                rowh = 1 + it * 400 + hi * 20;
            } else {
                const int ih = oh * S + dh - 1;
                if (ih < 0 || ih >= HH) continue;
                rowh = 1 + (it * HH + ih) * WW;
            }
            #pragma unroll
            for (int dw = 0; dw < 3; ++dw) {
                int rowoff;
                bool ok;
                if constexpr (COMPACT) {
                    const int wi = 3 * ow + dw - 1;
                    ok = active && (wi >= 0);
                    rowoff = rowh + wi;
                } else {
                    const int iw = ow * S + dw - 1;
                    ok = active && (iw >= 0);
                    rowoff = rowh + iw;
                }
                if (ok) {
                    bf16x8 v = *(const bf16x8*)(P + pbase + (size_t)rowoff * SRCSTRIDE);
                    const float* wp = wt + ((dt * 3 + dh) * 3 + dw) * 64 + c;
                    f32x4 w0 = *(const f32x4*)wp, w1 = *(const f32x4*)(wp + 4);
                    #pragma unroll
                    for (int e = 0; e < 4; ++e) {
                        acc[e]     += w0[e] * (float)v[e];
                        acc[4 + e] += w1[e] * (float)v[4 + e];
                    }
                }
            }
        }
    }
    float s = 0;
    #pragma unroll
    for (int e = 0; e < 8; ++e) s += acc[e];
    s += __shfl_xor(s, 1); s += __shfl_xor(s, 2); s += __shfl_xor(s, 4);
    const float mu = s * 0.015625f;
    float v2 = 0;
    #pragma unroll
    for (int e = 0; e < 8; ++e) { float d = acc[e] - mu; v2 += d * d; }
    v2 += __shfl_xor(v2, 1); v2 += __shfl_xor(v2, 2); v2 += __shfl_xor(v2, 4);
    const float rs = rsqrtf(v2 * 0.015625f + 1e-5f);
    if (active) {
        f32x4 g0 = *(const f32x4*)(gamma + c), g1 = *(const f32x4*)(gamma + c + 4);
        f32x4 b0 = *(const f32x4*)(beta + c),  b1 = *(const f32x4*)(beta + c + 4);
        bf16x8 o;
        #pragma unroll
        for (int e = 0; e < 4; ++e) {
            o[e]     = (bf16)(((acc[e]     - mu) * rs * g0[e] + b0[e]) * outScale);
            o[4 + e] = (bf16)(((acc[4 + e] - mu) * rs * g1[e] + b1[e]) * outScale);
        }
        const int p = 1 + (t * OH + oh) * OW + ow;
        *(bf16x8*)(outp + ((size_t)bh * NPpad + p) * HD + c) = o;
    }
}

// ---------------- merged pools: q (5400 blks) + k (1368) + v (1368) ----------------
__global__ __launch_bounds__(256) void pools_all(const bf16* __restrict__ tmpq,
                                                 const bf16* __restrict__ tmpkv,
                                                 const float* __restrict__ wt,
                                                 const float* __restrict__ gq, const float* __restrict__ bq,
                                                 const float* __restrict__ gk, const float* __restrict__ bk,
                                                 const float* __restrict__ gv, const float* __restrict__ bv,
                                                 bf16* __restrict__ qn, bf16* __restrict__ kn,
                                                 bf16* __restrict__ vnb) {
    const int w = threadIdx.x >> 6, lane = threadIdx.x & 63;
    const int bid = blockIdx.x;
    if (bid < 5400) {
        const int gw = xcd_remap(bid, 5400) * 4 + w;
        pool_body<2, 14, 14, 2, NQ, NQP, 768, false>(gw, lane, tmpq, wt, gq, bq, qn, 0.125f);
    } else if (bid < 6768) {
        const int gw = xcd_remap(bid - 5400, 1368) * 4 + w;
        pool_body<4, 7, 7, 1, NK, NKP, 1536, true>(gw, lane, tmpkv, wt + 1728, gk, bk, kn, 1.0f);
    } else {
        const int gw = xcd_remap(bid - 6768, 1368) * 4 + w;
        pool_body<4, 7, 7, 1, NK, NKP, 1536, true>(gw, lane, tmpkv + 768, wt + 3456, gv, bv, vnb, 1.0f);
    }
}

// ---------------- flash attention, fixed-max softmax (r11, unchanged) ----------------
__global__ __launch_bounds__(256) void attn_kernel(const bf16* __restrict__ qn,
                                                   const bf16* __restrict__ kn,
                                                   const bf16* __restrict__ vn,
                                                   bf16* __restrict__ ob,
                                                   const float* __restrict__ Mptr) {
    __shared__ bf16 Kl[2][32][72];
    __shared__ bf16 Vt[2][64][40];
    __shared__ bf16 Pl[4][16][40];

    const int tid = threadIdx.x, l = tid & 63, w = tid >> 6;
    const int li = l & 15, lg = l >> 4;
    const int wgid = xcd_remap(blockIdx.x, gridDim.x);
    const int bh = wgid / 25;
    const int b = bh / NH, head = bh % NH;
    const int qbase = (wgid % 25) * 64 + w * 16;
    const float M = Mptr[0];

    const bf16* qp = qn + ((size_t)bh * NQP + qbase + li) * HD + lg * 8;
    const bf16x8 aq0 = *(const bf16x8*)qp;
    const bf16x8 aq1 = *(const bf16x8*)(qp + 32);

    const int srow = tid >> 3, scol = (tid & 7) * 8;
    const int sj = tid & 31, sd8 = tid >> 5;
    const bf16* kbase = kn + (size_t)bh * NKP * HD;
    const bf16* vbase = vn + (size_t)bh * NKP * HD;

    u32x4 kv = *(const u32x4*)(kbase + srow * HD + scol);
    u32x4 vv = *(const u32x4*)(vbase + sj * HD + sd8 * 8);
    *(u32x4*)&Kl[0][srow][scol] = kv;
    {
        bf16x8 t = __builtin_bit_cast(bf16x8, vv);
        #pragma unroll
        for (int e = 0; e < 8; ++e) Vt[0][sd8 * 8 + e][sj] = t[e];
    }

    f32x4 oacc[4] = {};
    float lpart[4] = {0.f, 0.f, 0.f, 0.f};

    for (int kt = 0; kt < 13; ++kt) {
        const int cur = kt & 1;
        if (kt < 12) {
            kv = *(const u32x4*)(kbase + (kt + 1) * 32 * HD + srow * HD + scol);
            vv = *(const u32x4*)(vbase + (kt + 1) * 32 * HD + sj * HD + sd8 * 8);
        }
        __syncthreads();

        f32x4 c0 = {}, c1 = {};
        const bf16x8 b00 = *(const bf16x8*)&Kl[cur][li][lg * 8];
        const bf16x8 b01 = *(const bf16x8*)&Kl[cur][li][32 + lg * 8];
        const bf16x8 b10 = *(const bf16x8*)&Kl[cur][16 + li][lg * 8];
        const bf16x8 b11 = *(const bf16x8*)&Kl[cur][16 + li][32 + lg * 8];
        __builtin_amdgcn_s_setprio(1);
        c0 = MFMA16(aq0, b00, c0); c0 = MFMA16(aq1, b01, c0);
        c1 = MFMA16(aq0, b10, c1); c1 = MFMA16(aq1, b11, c1);
        __builtin_amdgcn_s_setprio(0);

        float p0[4], p1[4];
        #pragma unroll
        for (int r = 0; r < 4; ++r) {
            p0[r] = __expf(c0[r] - M);
            p1[r] = __expf(c1[r] - M);
        }
        if (kt == 12) {
            const bool m0 = (384 + li) >= NK;
            #pragma unroll
            for (int r = 0; r < 4; ++r) { if (m0) p0[r] = 0.f; p1[r] = 0.f; }
        }
        #pragma unroll
        for (int r = 0; r < 4; ++r) {
            lpart[r] += p0[r] + p1[r];
            Pl[w][lg * 4 + r][li]      = (bf16)p0[r];
            Pl[w][lg * 4 + r][16 + li] = (bf16)p1[r];
        }
        const bf16x8 ap = *(const bf16x8*)&Pl[w][li][lg * 8];
        __builtin_amdgcn_s_setprio(1);
        #pragma unroll
        for (int dg = 0; dg < 4; ++dg) {
            const bf16x8 bv = *(const bf16x8*)&Vt[cur][dg * 16 + li][lg * 8];
            oacc[dg] = MFMA16(ap, bv, oacc[dg]);
        }
        __builtin_amdgcn_s_setprio(0);

        if (kt < 12) {
            const int nxt = cur ^ 1;
            *(u32x4*)&Kl[nxt][srow][scol] = kv;
            bf16x8 t = __builtin_bit_cast(bf16x8, vv);
            #pragma unroll
            for (int e = 0; e < 8; ++e) Vt[nxt][sd8 * 8 + e][sj] = t[e];
        }
    }
    #pragma unroll
    for (int r = 0; r < 4; ++r) {
        float lsum = lpart[r];
        lsum += __shfl_xor(lsum, 1);
        lsum += __shfl_xor(lsum, 2);
        lsum += __shfl_xor(lsum, 4);
        lsum += __shfl_xor(lsum, 8);
        const int q = qbase + lg * 4 + r;
        if (q < NQ) {
            const float inv = 1.f / lsum;
            const size_t off = ((size_t)(b * NQ + q)) * CC + head * HD;
            #pragma unroll
            for (int dg = 0; dg < 4; ++dg)
                ob[off + dg * 16 + li] = (bf16)(oacc[dg][r] * inv);
        }
    }
}

// ---------------- launcher ----------------
extern "C" void kernel_launch(void* const* d_in, const int* in_sizes, int n_in,
                              void* d_out, int out_size, void* d_ws, size_t ws_size,
                              hipStream_t stream) {
    const float* x     = (const float*)d_in[0];
    const float* Wq    = (const float*)d_in[1];
    const float* Wk    = (const float*)d_in[2];
    const float* Wv    = (const float*)d_in[3];
    const float* Wproj = (const float*)d_in[4];
    const float* bproj = (const float*)d_in[5];
    const float* pqw   = (const float*)d_in[6];
    const float* pkw   = (const float*)d_in[7];
    const float* pvw   = (const float*)d_in[8];
    const float* gq    = (const float*)d_in[9];
    const float* bq    = (const float*)d_in[10];
    const float* gk    = (const float*)d_in[11];
    const float* bk    = (const float*)d_in[12];
    const float* gv    = (const float*)d_in[13];
    const float* bv    = (const float*)d_in[14];

    if (ws_size < 364000000ULL) return;
    char* ws = (char*)d_ws;
    bf16* xb    = (bf16*)(ws);               // [50304][768]
    bf16* wqkv  = (bf16*)(ws + 77266944);    // [2304][768] + wpb contiguous
    bf16* wpb   = (bf16*)(ws + 80805888);    // [768][768]
    bf16* tmpq  = (bf16*)(ws + 81985536);    // [50304][768]
    bf16* tmpkv = (bf16*)(ws + 159252480);   // [25856][1536]
    bf16* qn    = (bf16*)(ws + 238682112);   // [96][1600][64]
    bf16* kn    = (bf16*)(ws + 258342912);   // [96][416][64]
    bf16* vnb   = (bf16*)(ws + 263454720);   // [96][416][64]
    bf16* ob    = (bf16*)(ws + 268566528);   // [12672][768]
    float* wt   = (float*)(ws + 288030720);  // [3][27][64] f32
    float* Mb   = (float*)(ws + 288051456);  // [1]

    (void)hipFuncSetAttribute((const void*)gemmU,
                              hipFuncAttributeMaxDynamicSharedMemorySize, 131072);
    (void)hipFuncSetAttribute((const void*)gemmF,
                              hipFuncAttributeMaxDynamicSharedMemorySize, 98304);

    prep_all<<<6422, 256, 0, stream>>>(x, Wq, Wk, Wv, Wproj, pqw, pkw, pvw,
                                       gq, bq, gk, bk, xb, wqkv, wt, Mb);

    gemmU<<<1197, 512, 131072, stream>>>(xb, wqkv, tmpq, tmpkv);

    pools_all<<<8136, 256, 0, stream>>>(tmpq, tmpkv, wt, gq, bq, gk, bk, gv, bv,
                                        qn, kn, vnb);

    attn_kernel<<<2400, 256, 0, stream>>>(qn, kn, vnb, ob, Mb);

    gemmF<<<50 * 6, 512, 98304, stream>>>(ob, wpb, (float*)d_out, bproj, 6, MO, MOP);
}

// Round 14
// 328.137 us; speedup vs baseline: 1.1378x; 1.0223x over previous
//
#include <hip/hip_runtime.h>

using bf16   = __bf16;
using bf16x4 = __attribute__((ext_vector_type(4))) __bf16;
using bf16x8 = __attribute__((ext_vector_type(8))) __bf16;
using f32x4  = __attribute__((ext_vector_type(4))) float;
using u32x4  = __attribute__((ext_vector_type(4))) unsigned int;

#define MFMA16(a,b,c) __builtin_amdgcn_mfma_f32_16x16x32_bf16((a),(b),(c),0,0,0)

__device__ inline void glds16(const void* g, void* l) {
    __builtin_amdgcn_global_load_lds(
        (__attribute__((address_space(1))) void*)(const_cast<void*>(g)),
        (__attribute__((address_space(3))) void*)(l), 16, 0, 0);
}

// bijective XCD-chunked remap (m204)
__device__ inline int xcd_remap(int bid, int nwg) {
    const int xcd = bid & 7, loc = bid >> 3;
    const int q8 = nwg >> 3, r8 = nwg & 7;
    return (xcd < r8 ? xcd * (q8 + 1) : r8 * (q8 + 1) + (xcd - r8) * q8) + loc;
}

// ---------------- constants ----------------
constexpr int CB   = 8;
constexpr int NH   = 12;
constexpr int CC   = 768;
constexpr int HD   = 64;
constexpr int TT   = 8, HH = 28, WW = 28;
constexpr int NTOK = TT*HH*WW + 1;      // 6273
constexpr int MX   = CB*NTOK;           // 50184
constexpr int MXP  = 50304;
constexpr int NQ   = 1569, NQP = 1600;
constexpr int NK   = 393,  NKP = 416;
constexpr int MO   = CB*NQ;             // 12552
constexpr int MOP  = 12672;
constexpr int CTOK = 1 + TT*20*20;      // 3201
constexpr int MKV  = CB*CTOK;           // 25608
constexpr int MKVP = 25856;

// ---------------- merged prep: x-cast + weight cast + wt transpose + bound ----------------
__global__ __launch_bounds__(256) void prep_all(const float* __restrict__ x,
                                                const float* __restrict__ Wq, const float* __restrict__ Wk,
                                                const float* __restrict__ Wv, const float* __restrict__ Wp,
                                                const float* __restrict__ pqw, const float* __restrict__ pkw,
                                                const float* __restrict__ pvw,
                                                const float* __restrict__ gq, const float* __restrict__ bq,
                                                const float* __restrict__ gk, const float* __restrict__ bk,
                                                bf16* __restrict__ xb, bf16* __restrict__ wdst,
                                                float* __restrict__ wt, float* __restrict__ Mb) {
    constexpr int WSZ = 589824;
    const int bid = blockIdx.x, tid = threadIdx.x;
    if (bid < 4096) {
        const int nvalid = MX * CC, ntotal = MXP * CC;
        int i = (bid * 256 + tid) * 4;
        const int stride = 4096 * 256 * 4;
        for (; i < ntotal; i += stride) {
            bf16x4 o;
            if (i + 3 < nvalid) {
                f32x4 v = *(const f32x4*)(x + i);
                #pragma unroll
                for (int e = 0; e < 4; ++e) o[e] = (bf16)v[e];
            } else {
                #pragma unroll
                for (int e = 0; e < 4; ++e) {
                    int k = i + e;
                    o[e] = (bf16)((k < nvalid) ? x[k] : 0.f);
                }
            }
            *(bf16x4*)(xb + i) = o;
        }
    } else if (bid < 6400) {
        int i = ((bid - 4096) * 256 + tid) * 4;
        const int setn = i / WSZ, j = i % WSZ;
        const float* src = (setn == 0) ? Wq : (setn == 1) ? Wk : (setn == 2) ? Wv : Wp;
        f32x4 v = *(const f32x4*)(src + j);
        bf16x4 o;
        #pragma unroll
        for (int e = 0; e < 4; ++e) o[e] = (bf16)v[e];
        *(bf16x4*)(wdst + i) = o;
    } else if (bid < 6421) {
        int i = (bid - 6400) * 256 + tid;
        if (i < 3 * 1728) {
            int setn = i / 1728, j = i % 1728;
            const float* src = (setn == 0) ? pqw : (setn == 1) ? pkw : pvw;
            int tap = j / 64, c = j % 64;
            wt[i] = src[c * 27 + tap];
        }
    } else if (tid < 64) {
        const int c = tid;
        float mgq = fabsf(gq[c]), sbq = bq[c] * bq[c];
        float mgk = fabsf(gk[c]), sbk = bk[c] * bk[c];
        #pragma unroll
        for (int m = 1; m < 64; m <<= 1) {
            mgq = fmaxf(mgq, __shfl_xor(mgq, m)); sbq += __shfl_xor(sbq, m);
            mgk = fmaxf(mgk, __shfl_xor(mgk, m)); sbk += __shfl_xor(sbk, m);
        }
        if (c == 0) {
            const float Bq = 8.f * mgq + sqrtf(sbq);
            const float Bk = 8.f * mgk + sqrtf(sbk);
            Mb[0] = 0.125f * Bq * Bk;
        }
    }
}

// ---------------- unified Q + gathered-KV projection GEMM (r13, unchanged) ----------------
__global__ __launch_bounds__(512, 2) void gemmU(const bf16* __restrict__ xb,
                                                const bf16* __restrict__ wqkv,
                                                bf16* __restrict__ tmpq,
                                                bf16* __restrict__ tmpkv) {
    extern __shared__ char lds[];
    const int wgid = xcd_remap(blockIdx.x, gridDim.x);   // 1197

    const int tid = threadIdx.x, lane = tid & 63, w = tid >> 6;
    const int li = lane & 15, lg = lane >> 4;
    const int wr = w >> 2, wc = w & 3;
    const int lr  = lane >> 3;
    const int lsw = ((lane & 7) ^ lr) << 3;

    const bool isQ = wgid < 591;
    int bm, bn, Mv, ldc;
    const bf16* Bb;
    bf16* C;
    if (isQ) { bm = wgid / 3;        bn = wgid % 3;        Mv = MXP;  ldc = 768;
               Bb = wqkv + (size_t)bn * 256 * 768;               C = tmpq; }
    else     { int t = wgid - 591;   bm = t / 6; bn = t % 6; Mv = MKVP; ldc = 1536;
               Bb = wqkv + (size_t)(768 + bn * 256) * 768;       C = tmpkv; }

    const bf16* abase[4];
    const bf16* bbase[4];
    #pragma unroll
    for (int h_ = 0; h_ < 4; ++h_) {
        int gr = bm * 256 + h_ * 64 + w * 8 + lr;
        size_t orig;
        if (isQ) {
            if (gr > MXP - 1) gr = MXP - 1;
            orig = (size_t)gr;
        } else {
            if (gr > MKV - 1) gr = MKV - 1;
            const unsigned b = (unsigned)gr / 3201u;
            const unsigned p = (unsigned)gr % 3201u;
            if (p == 0) orig = (size_t)b * NTOK;
            else {
                const unsigned q  = p - 1;
                const unsigned t2 = q / 400u, rem = q % 400u;
                const unsigned hi = rem / 20u, wi = rem % 20u;
                const int ih = 4 * (int)((hi + 1) / 3) + (int)((hi + 1) % 3) - 1;
                const int iw = 4 * (int)((wi + 1) / 3) + (int)((wi + 1) % 3) - 1;
                orig = (size_t)b * NTOK + 1 + ((size_t)t2 * HH + ih) * WW + iw;
            }
        }
        abase[h_] = xb + orig * 768 + lsw;
        bbase[h_] = Bb + (size_t)(h_ * 64 + w * 8 + lr) * 768 + lsw;
    }

    const int sw_  = (li & 7) << 4;
    const int swc0 = (lg * 16) ^ sw_;
    const int swc1 = (64 | (lg * 16)) ^ sw_;

#define STAGE_T(Tt, buf) do {                                                        \
        char* d_ = lds + (buf) * 65536;                                              \
        _Pragma("unroll")                                                            \
        for (int h_ = 0; h_ < 4; ++h_)                                               \
            glds16(abase[h_] + (size_t)(Tt) * 64, d_ + (h_ * 64 + w * 8) * 128);     \
        _Pragma("unroll")                                                            \
        for (int h_ = 0; h_ < 4; ++h_)                                               \
            glds16(bbase[h_] + (size_t)(Tt) * 64, d_ + 32768 + (h_ * 64 + w * 8) * 128); \
    } while (0)

    f32x4 acc[8][4] = {};
    bf16x8 aF[8], bF[4];

#define READ_K(sw)                                                                   \
    _Pragma("unroll") for (int mf = 0; mf < 8; ++mf)                                 \
        aF[mf] = *(const bf16x8*)(bufA + (size_t)(wr * 128 + mf * 16 + li) * 128 + (sw)); \
    _Pragma("unroll") for (int nf = 0; nf < 4; ++nf)                                 \
        bF[nf] = *(const bf16x8*)(bufB + (size_t)(wc * 64 + nf * 16 + li) * 128 + (sw));

#define MFMA_K()                                                                     \
    _Pragma("unroll") for (int mf = 0; mf < 8; ++mf)                                 \
    _Pragma("unroll") for (int nf = 0; nf < 4; ++nf)                                 \
        acc[mf][nf] = MFMA16(aF[mf], bF[nf], acc[mf][nf]);

    STAGE_T(0, 0);
    STAGE_T(1, 1);
    asm volatile("s_waitcnt vmcnt(8)" ::: "memory");
    __builtin_amdgcn_s_barrier();
    __builtin_amdgcn_sched_barrier(0);

    #pragma unroll
    for (int T = 0; T < 12; ++T) {
        const char* bufA = lds + (T & 1) * 65536;
        const char* bufB = bufA + 32768;
        if (T >= 1 && T < 11) STAGE_T(T + 1, (T + 1) & 1);
        READ_K(swc0);
        __builtin_amdgcn_s_setprio(1);
        MFMA_K();
        __builtin_amdgcn_s_setprio(0);
        READ_K(swc1);
        __builtin_amdgcn_s_setprio(1);
        MFMA_K();
        __builtin_amdgcn_s_setprio(0);
        asm volatile("s_waitcnt lgkmcnt(0)" ::: "memory");
        if (T < 11) asm volatile("s_waitcnt vmcnt(0)" ::: "memory");
        __builtin_amdgcn_s_barrier();
        __builtin_amdgcn_sched_barrier(0);
    }
#undef STAGE_T
#undef READ_K
#undef MFMA_K

    #pragma unroll
    for (int mf = 0; mf < 8; ++mf) {
        const int row0 = bm * 256 + wr * 128 + mf * 16 + lg * 4;
        #pragma unroll
        for (int nf = 0; nf < 4; ++nf) {
            const int col = bn * 256 + wc * 64 + nf * 16 + li;
            #pragma unroll
            for (int r = 0; r < 4; ++r) {
                const int row = row0 + r;
                if (row < Mv)
                    C[(size_t)row * ldc + col] = (bf16)acc[mf][nf][r];
            }
        }
    }
}

// ---------------- final projection GEMM: 256x128 tile (r13, unchanged) ----------------
__global__ __launch_bounds__(512, 2) void gemmF(const bf16* __restrict__ A,
                                                const bf16* __restrict__ Bw,
                                                float* __restrict__ Cptr,
                                                const float* __restrict__ bias,
                                                int nbn, int Mvalid, int Aclamp) {
    extern __shared__ char lds[];
    const int wgid = xcd_remap(blockIdx.x, gridDim.x);
    const int bm = wgid / nbn, bn = wgid % nbn;

    const int tid = threadIdx.x, lane = tid & 63, w = tid >> 6;
    const int li = lane & 15, lg = lane >> 4;
    const int wr = w >> 2, wc = w & 3;
    const int lr  = lane >> 3;
    const int lsw = ((lane & 7) ^ lr) << 3;
    const bf16* Agp = A  + (size_t)bm * 256 * 768;
    const bf16* Bgp = Bw + (size_t)bn * 128 * 768;
    const int clampA = Aclamp - bm * 256;

    const int sw_  = (li & 7) << 4;
    const int swc0 = (lg * 16) ^ sw_;
    const int swc1 = (64 | (lg * 16)) ^ sw_;

#define STAGE_T(Tt, buf) do {                                                        \
        char* d_ = lds + (buf) * 49152;                                              \
        _Pragma("unroll")                                                            \
        for (int h_ = 0; h_ < 4; ++h_) {                                             \
            const int r0_ = h_ * 64 + w * 8;                                         \
            int gr_ = r0_ + lr; if (gr_ >= clampA) gr_ = clampA - 1;                 \
            glds16(Agp + (size_t)gr_ * 768 + (Tt) * 64 + lsw, d_ + r0_ * 128);       \
        }                                                                            \
        _Pragma("unroll")                                                            \
        for (int h_ = 0; h_ < 2; ++h_) {                                             \
            const int r0_ = h_ * 64 + w * 8;                                         \
            glds16(Bgp + (size_t)(r0_ + lr) * 768 + (Tt) * 64 + lsw,                 \
                   d_ + 32768 + r0_ * 128);                                          \
        } } while (0)

    f32x4 acc[8][2] = {};
    bf16x8 aF[8], bF[2];

#define READ_K(sw)                                                                   \
    _Pragma("unroll") for (int mf = 0; mf < 8; ++mf)                                 \
        aF[mf] = *(const bf16x8*)(bufA + (size_t)(wr * 128 + mf * 16 + li) * 128 + (sw)); \
    _Pragma("unroll") for (int nf = 0; nf < 2; ++nf)                                 \
        bF[nf] = *(const bf16x8*)(bufB + (size_t)(wc * 32 + nf * 16 + li) * 128 + (sw));

#define MFMA_K()                                                                     \
    _Pragma("unroll") for (int mf = 0; mf < 8; ++mf)                                 \
    _Pragma("unroll") for (int nf = 0; nf < 2; ++nf)                                 \
        acc[mf][nf] = MFMA16(aF[mf], bF[nf], acc[mf][nf]);

    STAGE_T(0, 0);
    STAGE_T(1, 1);
    asm volatile("s_waitcnt vmcnt(6)" ::: "memory");
    __builtin_amdgcn_s_barrier();
    __builtin_amdgcn_sched_barrier(0);

    #pragma unroll
    for (int T = 0; T < 12; ++T) {
        const char* bufA = lds + (T & 1) * 49152;
        const char* bufB = bufA + 32768;
        if (T >= 1 && T < 11) STAGE_T(T + 1, (T + 1) & 1);
        READ_K(swc0);
        __builtin_amdgcn_s_setprio(1);
        MFMA_K();
        __builtin_amdgcn_s_setprio(0);
        READ_K(swc1);
        __builtin_amdgcn_s_setprio(1);
        MFMA_K();
        __builtin_amdgcn_s_setprio(0);
        asm volatile("s_waitcnt lgkmcnt(0)" ::: "memory");
        if (T < 11) asm volatile("s_waitcnt vmcnt(0)" ::: "memory");
        __builtin_amdgcn_s_barrier();
        __builtin_amdgcn_sched_barrier(0);
    }
#undef STAGE_T
#undef READ_K
#undef MFMA_K

    #pragma unroll
    for (int mf = 0; mf < 8; ++mf) {
        const int row0 = bm * 256 + wr * 128 + mf * 16 + lg * 4;
        #pragma unroll
        for (int nf = 0; nf < 2; ++nf) {
            const int col = bn * 128 + wc * 32 + nf * 16 + li;
            #pragma unroll
            for (int r = 0; r < 4; ++r) {
                const int row = row0 + r;
                if (row < Mvalid)
                    Cptr[(size_t)row * 768 + col] = acc[mf][nf][r] + bias[col];
            }
        }
    }
}

// ---------------- pool body v2: 2 consecutive t outputs per lane (18 loads/output) ----------------
// task = tp*(OH*CH) + oh*CH + chunk; t0 = 2*tp, t1 = 2*tp+1. Input planes
// it = 2tp-1+pl, pl in 0..3; tap index dt0 = pl (valid pl<=2), dt1 = pl-1 (valid pl>=1).
template<int S, int OH, int OW, int CH, int NP, int NPpad, int SRCSTRIDE, bool COMPACT>
__device__ __forceinline__ void pool_body2(int gw, int lane,
                                           const bf16* __restrict__ P,
                                           const float* __restrict__ wt,
                                           const float* __restrict__ gamma,
                                           const float* __restrict__ beta,
                                           bf16* __restrict__ outp,
                                           float outScale) {
    constexpr int TASKS = 4 * OH * CH + 1;
    const int bh = gw / TASKS, task = gw % TASKS;
    const int b = bh / NH, head = bh % NH;
    const int owg = lane >> 3, cg = lane & 7, c = cg * 8;
    const size_t rowbase = COMPACT ? (size_t)b * CTOK : (size_t)b * NTOK;
    const size_t pbase = rowbase * SRCSTRIDE + head * HD + c;

    if (task == TASKS - 1) {   // cls + pad
        if (owg == 0) {
            bf16x8 v = *(const bf16x8*)(P + pbase);
            float a[8];
            #pragma unroll
            for (int e = 0; e < 8; ++e) a[e] = (float)v[e];
            float s = 0;
            #pragma unroll
            for (int e = 0; e < 8; ++e) s += a[e];
            s += __shfl_xor(s, 1); s += __shfl_xor(s, 2); s += __shfl_xor(s, 4);
            const float mu = s * 0.015625f;
            float v2 = 0;
            #pragma unroll
            for (int e = 0; e < 8; ++e) { float d = a[e] - mu; v2 += d * d; }
            v2 += __shfl_xor(v2, 1); v2 += __shfl_xor(v2, 2); v2 += __shfl_xor(v2, 4);
            const float rs = rsqrtf(v2 * 0.015625f + 1e-5f);
            f32x4 g0 = *(const f32x4*)(gamma + c), g1 = *(const f32x4*)(gamma + c + 4);
            f32x4 b0 = *(const f32x4*)(beta + c),  b1 = *(const f32x4*)(beta + c + 4);
            bf16x8 o;
            #pragma unroll
            for (int e = 0; e < 4; ++e) {
                o[e]     = (bf16)(((a[e]     - mu) * rs * g0[e] + b0[e]) * outScale);
                o[4 + e] = (bf16)(((a[4 + e] - mu) * rs * g1[e] + b1[e]) * outScale);
            }
            *(bf16x8*)(outp + ((size_t)bh * NPpad) * HD + c) = o;
        } else {
            bf16x8 z = {};
            for (int p = NP + owg - 1; p < NPpad; p += 7)
                *(bf16x8*)(outp + ((size_t)bh * NPpad + p) * HD + c) = z;
        }
        return;
    }

    const int tp = task / (OH * CH);
    const int r2 = task % (OH * CH);
    const int oh = r2 / CH;
    const int ow = (r2 % CH) * 8 + owg;
    const bool active = (ow < OW);

    float acc0[8] = {}, acc1[8] = {};
    #pragma unroll
    for (int pl = 0; pl < 4; ++pl) {
        const int it = 2 * tp - 1 + pl;
        if (it < 0 || it >= TT) continue;     // only trips at tp edges
        #pragma unroll
        for (int dh = 0; dh < 3; ++dh) {
            int rowh;
            if constexpr (COMPACT) {
                const int hi = 3 * oh + dh - 1;
                if (hi < 0) continue;
                rowh = 1 + it * 400 + hi * 20;
            } else {
                const int ih = oh * S + dh - 1;
                if (ih < 0 || ih >= HH) continue;
                rowh = 1 + (it * HH + ih) * WW;
            }
            #pragma unroll
            for (int dw = 0; dw < 3; ++dw) {
                int rowoff;
                bool ok;
                if constexpr (COMPACT) {
                    const int wi = 3 * ow + dw - 1;
                    ok = active && (wi >= 0);
                    rowoff = rowh + wi;
                } else {
                    const int iw = ow * S + dw - 1;
                    ok = active && (iw >= 0);
                    rowoff = rowh + iw;
                }
                if (ok) {
                    bf16x8 v = *(const bf16x8*)(P + pbase + (size_t)rowoff * SRCSTRIDE);
                    float fv[8];
                    #pragma unroll
                    for (int e = 0; e < 8; ++e) fv[e] = (float)v[e];
                    if (pl <= 2) {
                        const float* wp = wt + ((pl * 3 + dh) * 3 + dw) * 64 + c;
                        f32x4 w0 = *(const f32x4*)wp, w1 = *(const f32x4*)(wp + 4);
                        #pragma unroll
                        for (int e = 0; e < 4; ++e) {
                            acc0[e]     += w0[e] * fv[e];
                            acc0[4 + e] += w1[e] * fv[4 + e];
                        }
                    }
                    if (pl >= 1) {
                        const float* wp = wt + (((pl - 1) * 3 + dh) * 3 + dw) * 64 + c;
                        f32x4 w0 = *(const f32x4*)wp, w1 = *(const f32x4*)(wp + 4);
                        #pragma unroll
                        for (int e = 0; e < 4; ++e) {
                            acc1[e]     += w0[e] * fv[e];
                            acc1[4 + e] += w1[e] * fv[4 + e];
                        }
                    }
                }
            }
        }
    }
    // LN + store for both t outputs (t0 = 2tp, t1 = 2tp+1; both always < TT)
    f32x4 g0 = *(const f32x4*)(gamma + c), g1 = *(const f32x4*)(gamma + c + 4);
    f32x4 b0 = *(const f32x4*)(beta + c),  b1 = *(const f32x4*)(beta + c + 4);
    #pragma unroll
    for (int half = 0; half < 2; ++half) {
        float* acc = half ? acc1 : acc0;
        float s = 0;
        #pragma unroll
        for (int e = 0; e < 8; ++e) s += acc[e];
        s += __shfl_xor(s, 1); s += __shfl_xor(s, 2); s += __shfl_xor(s, 4);
        const float mu = s * 0.015625f;
        float v2 = 0;
        #pragma unroll
        for (int e = 0; e < 8; ++e) { float d = acc[e] - mu; v2 += d * d; }
        v2 += __shfl_xor(v2, 1); v2 += __shfl_xor(v2, 2); v2 += __shfl_xor(v2, 4);
        const float rs = rsqrtf(v2 * 0.015625f + 1e-5f);
        if (active) {
            bf16x8 o;
            #pragma unroll
            for (int e = 0; e < 4; ++e) {
                o[e]     = (bf16)(((acc[e]     - mu) * rs * g0[e] + b0[e]) * outScale);
                o[4 + e] = (bf16)(((acc[4 + e] - mu) * rs * g1[e] + b1[e]) * outScale);
            }
            const int p = 1 + ((2 * tp + half) * OH + oh) * OW + ow;
            *(bf16x8*)(outp + ((size_t)bh * NPpad + p) * HD + c) = o;
        }
    }
}

// ---------------- merged pools: q (2712 blks) + k (696) + v (696) ----------------
__global__ __launch_bounds__(256) void pools_all(const bf16* __restrict__ tmpq,
                                                 const bf16* __restrict__ tmpkv,
                                                 const float* __restrict__ wt,
                                                 const float* __restrict__ gq, const float* __restrict__ bq,
                                                 const float* __restrict__ gk, const float* __restrict__ bk,
                                                 const float* __restrict__ gv, const float* __restrict__ bv,
                                                 bf16* __restrict__ qn, bf16* __restrict__ kn,
                                                 bf16* __restrict__ vnb) {
    const int w = threadIdx.x >> 6, lane = threadIdx.x & 63;
    const int bid = blockIdx.x;
    if (bid < 2712) {
        const int gw = xcd_remap(bid, 2712) * 4 + w;        // 96 bh x 113 tasks
        pool_body2<2, 14, 14, 2, NQ, NQP, 768, false>(gw, lane, tmpq, wt, gq, bq, qn, 0.125f);
    } else if (bid < 3408) {
        const int gw = xcd_remap(bid - 2712, 696) * 4 + w;  // 96 bh x 29 tasks
        pool_body2<4, 7, 7, 1, NK, NKP, 1536, true>(gw, lane, tmpkv, wt + 1728, gk, bk, kn, 1.0f);
    } else {
        const int gw = xcd_remap(bid - 3408, 696) * 4 + w;
        pool_body2<4, 7, 7, 1, NK, NKP, 1536, true>(gw, lane, tmpkv + 768, wt + 3456, gv, bv, vnb, 1.0f);
    }
}

// ---------------- flash attention, fixed-max softmax (r13, unchanged) ----------------
__global__ __launch_bounds__(256) void attn_kernel(const bf16* __restrict__ qn,
                                                   const bf16* __restrict__ kn,
                                                   const bf16* __restrict__ vn,
                                                   bf16* __restrict__ ob,
                                                   const float* __restrict__ Mptr) {
    __shared__ bf16 Kl[2][32][72];
    __shared__ bf16 Vt[2][64][40];
    __shared__ bf16 Pl[4][16][40];

    const int tid = threadIdx.x, l = tid & 63, w = tid >> 6;
    const int li = l & 15, lg = l >> 4;
    const int wgid = xcd_remap(blockIdx.x, gridDim.x);
    const int bh = wgid / 25;
    const int b = bh / NH, head = bh % NH;
    const int qbase = (wgid % 25) * 64 + w * 16;
    const float M = Mptr[0];

    const bf16* qp = qn + ((size_t)bh * NQP + qbase + li) * HD + lg * 8;
    const bf16x8 aq0 = *(const bf16x8*)qp;
    const bf16x8 aq1 = *(const bf16x8*)(qp + 32);

    const int srow = tid >> 3, scol = (tid & 7) * 8;
    const int sj = tid & 31, sd8 = tid >> 5;
    const bf16* kbase = kn + (size_t)bh * NKP * HD;
    const bf16* vbase = vn + (size_t)bh * NKP * HD;

    u32x4 kv = *(const u32x4*)(kbase + srow * HD + scol);
    u32x4 vv = *(const u32x4*)(vbase + sj * HD + sd8 * 8);
    *(u32x4*)&Kl[0][srow][scol] = kv;
    {
        bf16x8 t = __builtin_bit_cast(bf16x8, vv);
        #pragma unroll
        for (int e = 0; e < 8; ++e) Vt[0][sd8 * 8 + e][sj] = t[e];
    }

    f32x4 oacc[4] = {};
    float lpart[4] = {0.f, 0.f, 0.f, 0.f};

    for (int kt = 0; kt < 13; ++kt) {
        const int cur = kt & 1;
        if (kt < 12) {
            kv = *(const u32x4*)(kbase + (kt + 1) * 32 * HD + srow * HD + scol);
            vv = *(const u32x4*)(vbase + (kt + 1) * 32 * HD + sj * HD + sd8 * 8);
        }
        __syncthreads();

        f32x4 c0 = {}, c1 = {};
        const bf16x8 b00 = *(const bf16x8*)&Kl[cur][li][lg * 8];
        const bf16x8 b01 = *(const bf16x8*)&Kl[cur][li][32 + lg * 8];
        const bf16x8 b10 = *(const bf16x8*)&Kl[cur][16 + li][lg * 8];
        const bf16x8 b11 = *(const bf16x8*)&Kl[cur][16 + li][32 + lg * 8];
        __builtin_amdgcn_s_setprio(1);
        c0 = MFMA16(aq0, b00, c0); c0 = MFMA16(aq1, b01, c0);
        c1 = MFMA16(aq0, b10, c1); c1 = MFMA16(aq1, b11, c1);
        __builtin_amdgcn_s_setprio(0);

        float p0[4], p1[4];
        #pragma unroll
        for (int r = 0; r < 4; ++r) {
            p0[r] = __expf(c0[r] - M);
            p1[r] = __expf(c1[r] - M);
        }
        if (kt == 12) {
            const bool m0 = (384 + li) >= NK;
            #pragma unroll
            for (int r = 0; r < 4; ++r) { if (m0) p0[r] = 0.f; p1[r] = 0.f; }
        }
        #pragma unroll
        for (int r = 0; r < 4; ++r) {
            lpart[r] += p0[r] + p1[r];
            Pl[w][lg * 4 + r][li]      = (bf16)p0[r];
            Pl[w][lg * 4 + r][16 + li] = (bf16)p1[r];
        }
        const bf16x8 ap = *(const bf16x8*)&Pl[w][li][lg * 8];
        __builtin_amdgcn_s_setprio(1);
        #pragma unroll
        for (int dg = 0; dg < 4; ++dg) {
            const bf16x8 bv = *(const bf16x8*)&Vt[cur][dg * 16 + li][lg * 8];
            oacc[dg] = MFMA16(ap, bv, oacc[dg]);
        }
        __builtin_amdgcn_s_setprio(0);

        if (kt < 12) {
            const int nxt = cur ^ 1;
            *(u32x4*)&Kl[nxt][srow][scol] = kv;
            bf16x8 t = __builtin_bit_cast(bf16x8, vv);
            #pragma unroll
            for (int e = 0; e < 8; ++e) Vt[nxt][sd8 * 8 + e][sj] = t[e];
        }
    }
    #pragma unroll
    for (int r = 0; r < 4; ++r) {
        float lsum = lpart[r];
        lsum += __shfl_xor(lsum, 1);
        lsum += __shfl_xor(lsum, 2);
        lsum += __shfl_xor(lsum, 4);
        lsum += __shfl_xor(lsum, 8);
        const int q = qbase + lg * 4 + r;
        if (q < NQ) {
            const float inv = 1.f / lsum;
            const size_t off = ((size_t)(b * NQ + q)) * CC + head * HD;
            #pragma unroll
            for (int dg = 0; dg < 4; ++dg)
                ob[off + dg * 16 + li] = (bf16)(oacc[dg][r] * inv);
        }
    }
}

// ---------------- launcher ----------------
extern "C" void kernel_launch(void* const* d_in, const int* in_sizes, int n_in,
                              void* d_out, int out_size, void* d_ws, size_t ws_size,
                              hipStream_t stream) {
    const float* x     = (const float*)d_in[0];
    const float* Wq    = (const float*)d_in[1];
    const float* Wk    = (const float*)d_in[2];
    const float* Wv    = (const float*)d_in[3];
    const float* Wproj = (const float*)d_in[4];
    const float* bproj = (const float*)d_in[5];
    const float* pqw   = (const float*)d_in[6];
    const float* pkw   = (const float*)d_in[7];
    const float* pvw   = (const float*)d_in[8];
    const float* gq    = (const float*)d_in[9];
    const float* bq    = (const float*)d_in[10];
    const float* gk    = (const float*)d_in[11];
    const float* bk    = (const float*)d_in[12];
    const float* gv    = (const float*)d_in[13];
    const float* bv    = (const float*)d_in[14];

    if (ws_size < 364000000ULL) return;
    char* ws = (char*)d_ws;
    bf16* xb    = (bf16*)(ws);               // [50304][768]
    bf16* wqkv  = (bf16*)(ws + 77266944);    // [2304][768] + wpb contiguous
    bf16* wpb   = (bf16*)(ws + 80805888);    // [768][768]
    bf16* tmpq  = (bf16*)(ws + 81985536);    // [50304][768]
    bf16* tmpkv = (bf16*)(ws + 159252480);   // [25856][1536]
    bf16* qn    = (bf16*)(ws + 238682112);   // [96][1600][64]
    bf16* kn    = (bf16*)(ws + 258342912);   // [96][416][64]
    bf16* vnb   = (bf16*)(ws + 263454720);   // [96][416][64]
    bf16* ob    = (bf16*)(ws + 268566528);   // [12672][768]
    float* wt   = (float*)(ws + 288030720);  // [3][27][64] f32
    float* Mb   = (float*)(ws + 288051456);  // [1]

    (void)hipFuncSetAttribute((const void*)gemmU,
                              hipFuncAttributeMaxDynamicSharedMemorySize, 131072);
    (void)hipFuncSetAttribute((const void*)gemmF,
                              hipFuncAttributeMaxDynamicSharedMemorySize, 98304);

    prep_all<<<6422, 256, 0, stream>>>(x, Wq, Wk, Wv, Wproj, pqw, pkw, pvw,
                                       gq, bq, gk, bk, xb, wqkv, wt, Mb);

    gemmU<<<1197, 512, 131072, stream>>>(xb, wqkv, tmpq, tmpkv);

    pools_all<<<4104, 256, 0, stream>>>(tmpq, tmpkv, wt, gq, bq, gk, bk, gv, bv,
                                        qn, kn, vnb);

    attn_kernel<<<2400, 256, 0, stream>>>(qn, kn, vnb, ob, Mb);

    gemmF<<<50 * 6, 512, 98304, stream>>>(ob, wpb, (float*)d_out, bproj, 6, MO, MOP);
}

// Round 15
// 323.367 us; speedup vs baseline: 1.1546x; 1.0148x over previous
//
#include <hip/hip_runtime.h>

using bf16   = __bf16;
using bf16x4 = __attribute__((ext_vector_type(4))) __bf16;
using bf16x8 = __attribute__((ext_vector_type(8))) __bf16;
using f32x4  = __attribute__((ext_vector_type(4))) float;
using u32x4  = __attribute__((ext_vector_type(4))) unsigned int;

#define MFMA16(a,b,c) __builtin_amdgcn_mfma_f32_16x16x32_bf16((a),(b),(c),0,0,0)

__device__ inline void glds16(const void* g, void* l) {
    __builtin_amdgcn_global_load_lds(
        (__attribute__((address_space(1))) void*)(const_cast<void*>(g)),
        (__attribute__((address_space(3))) void*)(l), 16, 0, 0);
}

// bijective XCD-chunked remap (m204)
__device__ inline int xcd_remap(int bid, int nwg) {
    const int xcd = bid & 7, loc = bid >> 3;
    const int q8 = nwg >> 3, r8 = nwg & 7;
    return (xcd < r8 ? xcd * (q8 + 1) : r8 * (q8 + 1) + (xcd - r8) * q8) + loc;
}

// ---------------- constants ----------------
constexpr int CB   = 8;
constexpr int NH   = 12;
constexpr int CC   = 768;
constexpr int HD   = 64;
constexpr int TT   = 8, HH = 28, WW = 28;
constexpr int NTOK = TT*HH*WW + 1;      // 6273
constexpr int MX   = CB*NTOK;           // 50184
constexpr int MXP  = 50304;
constexpr int NQ   = 1569, NQP = 1600;
constexpr int NK   = 393,  NKP = 416;
constexpr int MO   = CB*NQ;             // 12552
constexpr int MOP  = 12672;
constexpr int CTOK = 1 + TT*20*20;      // 3201
constexpr int MKV  = CB*CTOK;           // 25608
constexpr int MKVP = 25856;

// ---------------- merged prep: x-cast + weight cast + wt transpose + bound ----------------
__global__ __launch_bounds__(256) void prep_all(const float* __restrict__ x,
                                                const float* __restrict__ Wq, const float* __restrict__ Wk,
                                                const float* __restrict__ Wv, const float* __restrict__ Wp,
                                                const float* __restrict__ pqw, const float* __restrict__ pkw,
                                                const float* __restrict__ pvw,
                                                const float* __restrict__ gq, const float* __restrict__ bq,
                                                const float* __restrict__ gk, const float* __restrict__ bk,
                                                bf16* __restrict__ xb, bf16* __restrict__ wdst,
                                                float* __restrict__ wt, float* __restrict__ Mb) {
    constexpr int WSZ = 589824;
    const int bid = blockIdx.x, tid = threadIdx.x;
    if (bid < 4096) {
        const int nvalid = MX * CC, ntotal = MXP * CC;
        int i = (bid * 256 + tid) * 4;
        const int stride = 4096 * 256 * 4;
        for (; i < ntotal; i += stride) {
            bf16x4 o;
            if (i + 3 < nvalid) {
                f32x4 v = *(const f32x4*)(x + i);
                #pragma unroll
                for (int e = 0; e < 4; ++e) o[e] = (bf16)v[e];
            } else {
                #pragma unroll
                for (int e = 0; e < 4; ++e) {
                    int k = i + e;
                    o[e] = (bf16)((k < nvalid) ? x[k] : 0.f);
                }
            }
            *(bf16x4*)(xb + i) = o;
        }
    } else if (bid < 6400) {
        int i = ((bid - 4096) * 256 + tid) * 4;
        const int setn = i / WSZ, j = i % WSZ;
        const float* src = (setn == 0) ? Wq : (setn == 1) ? Wk : (setn == 2) ? Wv : Wp;
        f32x4 v = *(const f32x4*)(src + j);
        bf16x4 o;
        #pragma unroll
        for (int e = 0; e < 4; ++e) o[e] = (bf16)v[e];
        *(bf16x4*)(wdst + i) = o;
    } else if (bid < 6421) {
        int i = (bid - 6400) * 256 + tid;
        if (i < 3 * 1728) {
            int setn = i / 1728, j = i % 1728;
            const float* src = (setn == 0) ? pqw : (setn == 1) ? pkw : pvw;
            int tap = j / 64, c = j % 64;
            wt[i] = src[c * 27 + tap];
        }
    } else if (tid < 64) {
        const int c = tid;
        float mgq = fabsf(gq[c]), sbq = bq[c] * bq[c];
        float mgk = fabsf(gk[c]), sbk = bk[c] * bk[c];
        #pragma unroll
        for (int m = 1; m < 64; m <<= 1) {
            mgq = fmaxf(mgq, __shfl_xor(mgq, m)); sbq += __shfl_xor(sbq, m);
            mgk = fmaxf(mgk, __shfl_xor(mgk, m)); sbk += __shfl_xor(sbk, m);
        }
        if (c == 0) {
            const float Bq = 8.f * mgq + sqrtf(sbq);
            const float Bk = 8.f * mgk + sqrtf(sbk);
            Mb[0] = 0.125f * Bq * Bk;
        }
    }
}

// ---------------- unified Q + gathered-KV projection GEMM (r13, unchanged) ----------------
__global__ __launch_bounds__(512, 2) void gemmU(const bf16* __restrict__ xb,
                                                const bf16* __restrict__ wqkv,
                                                bf16* __restrict__ tmpq,
                                                bf16* __restrict__ tmpkv) {
    extern __shared__ char lds[];
    const int wgid = xcd_remap(blockIdx.x, gridDim.x);   // 1197

    const int tid = threadIdx.x, lane = tid & 63, w = tid >> 6;
    const int li = lane & 15, lg = lane >> 4;
    const int wr = w >> 2, wc = w & 3;
    const int lr  = lane >> 3;
    const int lsw = ((lane & 7) ^ lr) << 3;

    const bool isQ = wgid < 591;
    int bm, bn, Mv, ldc;
    const bf16* Bb;
    bf16* C;
    if (isQ) { bm = wgid / 3;        bn = wgid % 3;        Mv = MXP;  ldc = 768;
               Bb = wqkv + (size_t)bn * 256 * 768;               C = tmpq; }
    else     { int t = wgid - 591;   bm = t / 6; bn = t % 6; Mv = MKVP; ldc = 1536;
               Bb = wqkv + (size_t)(768 + bn * 256) * 768;       C = tmpkv; }

    const bf16* abase[4];
    const bf16* bbase[4];
    #pragma unroll
    for (int h_ = 0; h_ < 4; ++h_) {
        int gr = bm * 256 + h_ * 64 + w * 8 + lr;
        size_t orig;
        if (isQ) {
            if (gr > MXP - 1) gr = MXP - 1;
            orig = (size_t)gr;
        } else {
            if (gr > MKV - 1) gr = MKV - 1;
            const unsigned b = (unsigned)gr / 3201u;
            const unsigned p = (unsigned)gr % 3201u;
            if (p == 0) orig = (size_t)b * NTOK;
            else {
                const unsigned q  = p - 1;
                const unsigned t2 = q / 400u, rem = q % 400u;
                const unsigned hi = rem / 20u, wi = rem % 20u;
                const int ih = 4 * (int)((hi + 1) / 3) + (int)((hi + 1) % 3) - 1;
                const int iw = 4 * (int)((wi + 1) / 3) + (int)((wi + 1) % 3) - 1;
                orig = (size_t)b * NTOK + 1 + ((size_t)t2 * HH + ih) * WW + iw;
            }
        }
        abase[h_] = xb + orig * 768 + lsw;
        bbase[h_] = Bb + (size_t)(h_ * 64 + w * 8 + lr) * 768 + lsw;
    }

    const int sw_  = (li & 7) << 4;
    const int swc0 = (lg * 16) ^ sw_;
    const int swc1 = (64 | (lg * 16)) ^ sw_;

#define STAGE_T(Tt, buf) do {                                                        \
        char* d_ = lds + (buf) * 65536;                                              \
        _Pragma("unroll")                                                            \
        for (int h_ = 0; h_ < 4; ++h_)                                               \
            glds16(abase[h_] + (size_t)(Tt) * 64, d_ + (h_ * 64 + w * 8) * 128);     \
        _Pragma("unroll")                                                            \
        for (int h_ = 0; h_ < 4; ++h_)                                               \
            glds16(bbase[h_] + (size_t)(Tt) * 64, d_ + 32768 + (h_ * 64 + w * 8) * 128); \
    } while (0)

    f32x4 acc[8][4] = {};
    bf16x8 aF[8], bF[4];

#define READ_K(sw)                                                                   \
    _Pragma("unroll") for (int mf = 0; mf < 8; ++mf)                                 \
        aF[mf] = *(const bf16x8*)(bufA + (size_t)(wr * 128 + mf * 16 + li) * 128 + (sw)); \
    _Pragma("unroll") for (int nf = 0; nf < 4; ++nf)                                 \
        bF[nf] = *(const bf16x8*)(bufB + (size_t)(wc * 64 + nf * 16 + li) * 128 + (sw));

#define MFMA_K()                                                                     \
    _Pragma("unroll") for (int mf = 0; mf < 8; ++mf)                                 \
    _Pragma("unroll") for (int nf = 0; nf < 4; ++nf)                                 \
        acc[mf][nf] = MFMA16(aF[mf], bF[nf], acc[mf][nf]);

    STAGE_T(0, 0);
    STAGE_T(1, 1);
    asm volatile("s_waitcnt vmcnt(8)" ::: "memory");
    __builtin_amdgcn_s_barrier();
    __builtin_amdgcn_sched_barrier(0);

    #pragma unroll
    for (int T = 0; T < 12; ++T) {
        const char* bufA = lds + (T & 1) * 65536;
        const char* bufB = bufA + 32768;
        if (T >= 1 && T < 11) STAGE_T(T + 1, (T + 1) & 1);
        READ_K(swc0);
        __builtin_amdgcn_s_setprio(1);
        MFMA_K();
        __builtin_amdgcn_s_setprio(0);
        READ_K(swc1);
        __builtin_amdgcn_s_setprio(1);
        MFMA_K();
        __builtin_amdgcn_s_setprio(0);
        asm volatile("s_waitcnt lgkmcnt(0)" ::: "memory");
        if (T < 11) asm volatile("s_waitcnt vmcnt(0)" ::: "memory");
        __builtin_amdgcn_s_barrier();
        __builtin_amdgcn_sched_barrier(0);
    }
#undef STAGE_T
#undef READ_K
#undef MFMA_K

    #pragma unroll
    for (int mf = 0; mf < 8; ++mf) {
        const int row0 = bm * 256 + wr * 128 + mf * 16 + lg * 4;
        #pragma unroll
        for (int nf = 0; nf < 4; ++nf) {
            const int col = bn * 256 + wc * 64 + nf * 16 + li;
            #pragma unroll
            for (int r = 0; r < 4; ++r) {
                const int row = row0 + r;
                if (row < Mv)
                    C[(size_t)row * ldc + col] = (bf16)acc[mf][nf][r];
            }
        }
    }
}

// ---------------- final projection GEMM: 256x128 tile (r13, unchanged) ----------------
__global__ __launch_bounds__(512, 2) void gemmF(const bf16* __restrict__ A,
                                                const bf16* __restrict__ Bw,
                                                float* __restrict__ Cptr,
                                                const float* __restrict__ bias,
                                                int nbn, int Mvalid, int Aclamp) {
    extern __shared__ char lds[];
    const int wgid = xcd_remap(blockIdx.x, gridDim.x);
    const int bm = wgid / nbn, bn = wgid % nbn;

    const int tid = threadIdx.x, lane = tid & 63, w = tid >> 6;
    const int li = lane & 15, lg = lane >> 4;
    const int wr = w >> 2, wc = w & 3;
    const int lr  = lane >> 3;
    const int lsw = ((lane & 7) ^ lr) << 3;
    const bf16* Agp = A  + (size_t)bm * 256 * 768;
    const bf16* Bgp = Bw + (size_t)bn * 128 * 768;
    const int clampA = Aclamp - bm * 256;

    const int sw_  = (li & 7) << 4;
    const int swc0 = (lg * 16) ^ sw_;
    const int swc1 = (64 | (lg * 16)) ^ sw_;

#define STAGE_T(Tt, buf) do {                                                        \
        char* d_ = lds + (buf) * 49152;                                              \
        _Pragma("unroll")                                                            \
        for (int h_ = 0; h_ < 4; ++h_) {                                             \
            const int r0_ = h_ * 64 + w * 8;                                         \
            int gr_ = r0_ + lr; if (gr_ >= clampA) gr_ = clampA - 1;                 \
            glds16(Agp + (size_t)gr_ * 768 + (Tt) * 64 + lsw, d_ + r0_ * 128);       \
        }                                                                            \
        _Pragma("unroll")                                                            \
        for (int h_ = 0; h_ < 2; ++h_) {                                             \
            const int r0_ = h_ * 64 + w * 8;                                         \
            glds16(Bgp + (size_t)(r0_ + lr) * 768 + (Tt) * 64 + lsw,                 \
                   d_ + 32768 + r0_ * 128);                                          \
        } } while (0)

    f32x4 acc[8][2] = {};
    bf16x8 aF[8], bF[2];

#define READ_K(sw)                                                                   \
    _Pragma("unroll") for (int mf = 0; mf < 8; ++mf)                                 \
        aF[mf] = *(const bf16x8*)(bufA + (size_t)(wr * 128 + mf * 16 + li) * 128 + (sw)); \
    _Pragma("unroll") for (int nf = 0; nf < 2; ++nf)                                 \
        bF[nf] = *(const bf16x8*)(bufB + (size_t)(wc * 32 + nf * 16 + li) * 128 + (sw));

#define MFMA_K()                                                                     \
    _Pragma("unroll") for (int mf = 0; mf < 8; ++mf)                                 \
    _Pragma("unroll") for (int nf = 0; nf < 2; ++nf)                                 \
        acc[mf][nf] = MFMA16(aF[mf], bF[nf], acc[mf][nf]);

    STAGE_T(0, 0);
    STAGE_T(1, 1);
    asm volatile("s_waitcnt vmcnt(6)" ::: "memory");
    __builtin_amdgcn_s_barrier();
    __builtin_amdgcn_sched_barrier(0);

    #pragma unroll
    for (int T = 0; T < 12; ++T) {
        const char* bufA = lds + (T & 1) * 49152;
        const char* bufB = bufA + 32768;
        if (T >= 1 && T < 11) STAGE_T(T + 1, (T + 1) & 1);
        READ_K(swc0);
        __builtin_amdgcn_s_setprio(1);
        MFMA_K();
        __builtin_amdgcn_s_setprio(0);
        READ_K(swc1);
        __builtin_amdgcn_s_setprio(1);
        MFMA_K();
        __builtin_amdgcn_s_setprio(0);
        asm volatile("s_waitcnt lgkmcnt(0)" ::: "memory");
        if (T < 11) asm volatile("s_waitcnt vmcnt(0)" ::: "memory");
        __builtin_amdgcn_s_barrier();
        __builtin_amdgcn_sched_barrier(0);
    }
#undef STAGE_T
#undef READ_K
#undef MFMA_K

    #pragma unroll
    for (int mf = 0; mf < 8; ++mf) {
        const int row0 = bm * 256 + wr * 128 + mf * 16 + lg * 4;
        #pragma unroll
        for (int nf = 0; nf < 2; ++nf) {
            const int col = bn * 128 + wc * 32 + nf * 16 + li;
            #pragma unroll
            for (int r = 0; r < 4; ++r) {
                const int row = row0 + r;
                if (row < Mvalid)
                    Cptr[(size_t)row * 768 + col] = acc[mf][nf][r] + bias[col];
            }
        }
    }
}

// ---------------- q-pool quad body: 2t x 2ow outputs per lane (15 loads/output) ----------------
// lane = owp(3b)*8 + cg(3b); owp in 0..6 active (7 ow-pairs cover OW=14).
// task = tp*14 + oh (tp in 0..3, oh in 0..13), +1 cls task. TASKS = 57.
// planes: it = 2tp-1+pl (pl 0..3); iw = 4owp-1+du (du 0..4).
// output (ht,hw): t=2tp+ht, ow=2owp+hw; taps dt=pl-ht, dw=du-2hw (each valid in [0,2]).
__device__ __forceinline__ void pool_q4(int gw, int lane,
                                        const bf16* __restrict__ P,
                                        const float* __restrict__ wt,
                                        const float* __restrict__ gamma,
                                        const float* __restrict__ beta,
                                        bf16* __restrict__ outp) {
    constexpr int TASKS = 57;
    const int bh = gw / TASKS, task = gw % TASKS;
    const int b = bh / NH, head = bh % NH;
    const int owp = lane >> 3, cg = lane & 7, c = cg * 8;
    const size_t pbase = (size_t)b * NTOK * 768 + head * HD + c;

    if (task == TASKS - 1) {   // cls + pad (same lane roles as r14)
        if (owp == 0) {
            bf16x8 v = *(const bf16x8*)(P + pbase);
            float a[8];
            #pragma unroll
            for (int e = 0; e < 8; ++e) a[e] = (float)v[e];
            float s = 0;
            #pragma unroll
            for (int e = 0; e < 8; ++e) s += a[e];
            s += __shfl_xor(s, 1); s += __shfl_xor(s, 2); s += __shfl_xor(s, 4);
            const float mu = s * 0.015625f;
            float v2 = 0;
            #pragma unroll
            for (int e = 0; e < 8; ++e) { float d = a[e] - mu; v2 += d * d; }
            v2 += __shfl_xor(v2, 1); v2 += __shfl_xor(v2, 2); v2 += __shfl_xor(v2, 4);
            const float rs = rsqrtf(v2 * 0.015625f + 1e-5f);
            f32x4 g0 = *(const f32x4*)(gamma + c), g1 = *(const f32x4*)(gamma + c + 4);
            f32x4 b0 = *(const f32x4*)(beta + c),  b1 = *(const f32x4*)(beta + c + 4);
            bf16x8 o;
            #pragma unroll
            for (int e = 0; e < 4; ++e) {
                o[e]     = (bf16)(((a[e]     - mu) * rs * g0[e] + b0[e]) * 0.125f);
                o[4 + e] = (bf16)(((a[4 + e] - mu) * rs * g1[e] + b1[e]) * 0.125f);
            }
            *(bf16x8*)(outp + ((size_t)bh * NQP) * HD + c) = o;
        } else {
            bf16x8 z = {};
            for (int p = NQ + owp - 1; p < NQP; p += 7)
                *(bf16x8*)(outp + ((size_t)bh * NQP + p) * HD + c) = z;
        }
        return;
    }

    const int tp = task / 14, oh = task % 14;
    const bool active = (owp < 7);

    float a00[8] = {}, a01[8] = {}, a10[8] = {}, a11[8] = {};
    #pragma unroll
    for (int pl = 0; pl < 4; ++pl) {
        const int it = 2 * tp - 1 + pl;
        if (it < 0 || it >= TT) continue;
        #pragma unroll
        for (int dh = 0; dh < 3; ++dh) {
            const int ih = 2 * oh + dh - 1;
            if (ih < 0 || ih >= HH) continue;
            const int rowh = 1 + (it * HH + ih) * WW;
            #pragma unroll
            for (int du = 0; du < 5; ++du) {
                const int iw = 4 * owp - 1 + du;
                if (active && iw >= 0 && iw < WW) {
                    bf16x8 v = *(const bf16x8*)(P + pbase + (size_t)(rowh + iw) * 768);
                    float fv[8];
                    #pragma unroll
                    for (int e = 0; e < 8; ++e) fv[e] = (float)v[e];
#define TAP(ACC, DT, DW) do {                                                        \
        const float* wp_ = wt + (((DT) * 3 + dh) * 3 + (DW)) * 64 + c;               \
        f32x4 w0_ = *(const f32x4*)wp_, w1_ = *(const f32x4*)(wp_ + 4);              \
        _Pragma("unroll")                                                            \
        for (int e = 0; e < 4; ++e) {                                                \
            ACC[e]     += w0_[e] * fv[e];                                            \
            ACC[4 + e] += w1_[e] * fv[4 + e];                                        \
        } } while (0)
                    if (du <= 2) {
                        if (pl <= 2) TAP(a00, pl,     du);
                        if (pl >= 1) TAP(a10, pl - 1, du);
                    }
                    if (du >= 2) {
                        if (pl <= 2) TAP(a01, pl,     du - 2);
                        if (pl >= 1) TAP(a11, pl - 1, du - 2);
                    }
#undef TAP
                }
            }
        }
    }
    // LN + store for the 4 outputs
    f32x4 g0 = *(const f32x4*)(gamma + c), g1 = *(const f32x4*)(gamma + c + 4);
    f32x4 b0 = *(const f32x4*)(beta + c),  b1 = *(const f32x4*)(beta + c + 4);
#define LNSTORE(ACC, HT, HW) do {                                                    \
        float s_ = 0;                                                                \
        _Pragma("unroll") for (int e = 0; e < 8; ++e) s_ += ACC[e];                  \
        s_ += __shfl_xor(s_, 1); s_ += __shfl_xor(s_, 2); s_ += __shfl_xor(s_, 4);   \
        const float mu_ = s_ * 0.015625f;                                            \
        float v2_ = 0;                                                               \
        _Pragma("unroll") for (int e = 0; e < 8; ++e) {                              \
            float d_ = ACC[e] - mu_; v2_ += d_ * d_; }                               \
        v2_ += __shfl_xor(v2_, 1); v2_ += __shfl_xor(v2_, 2); v2_ += __shfl_xor(v2_, 4); \
        const float rs_ = rsqrtf(v2_ * 0.015625f + 1e-5f);                           \
        if (active) {                                                                \
            bf16x8 o_;                                                               \
            _Pragma("unroll") for (int e = 0; e < 4; ++e) {                          \
                o_[e]     = (bf16)(((ACC[e]     - mu_) * rs_ * g0[e] + b0[e]) * 0.125f); \
                o_[4 + e] = (bf16)(((ACC[4 + e] - mu_) * rs_ * g1[e] + b1[e]) * 0.125f); \
            }                                                                        \
            const int p_ = 1 + ((2 * tp + (HT)) * 14 + oh) * 14 + (2 * owp + (HW));  \
            *(bf16x8*)(outp + ((size_t)bh * NQP + p_) * HD + c) = o_;                \
        } } while (0)
    LNSTORE(a00, 0, 0);
    LNSTORE(a01, 0, 1);
    LNSTORE(a10, 1, 0);
    LNSTORE(a11, 1, 1);
#undef LNSTORE
}

// ---------------- k/v pool body: 2 consecutive t outputs per lane (r14, unchanged) ----------------
template<int S, int OH, int OW, int CH, int NP, int NPpad, int SRCSTRIDE, bool COMPACT>
__device__ __forceinline__ void pool_body2(int gw, int lane,
                                           const bf16* __restrict__ P,
                                           const float* __restrict__ wt,
                                           const float* __restrict__ gamma,
                                           const float* __restrict__ beta,
                                           bf16* __restrict__ outp,
                                           float outScale) {
    constexpr int TASKS = 4 * OH * CH + 1;
    const int bh = gw / TASKS, task = gw % TASKS;
    const int b = bh / NH, head = bh % NH;
    const int owg = lane >> 3, cg = lane & 7, c = cg * 8;
    const size_t rowbase = COMPACT ? (size_t)b * CTOK : (size_t)b * NTOK;
    const size_t pbase = rowbase * SRCSTRIDE + head * HD + c;

    if (task == TASKS - 1) {
        if (owg == 0) {
            bf16x8 v = *(const bf16x8*)(P + pbase);
            float a[8];
            #pragma unroll
            for (int e = 0; e < 8; ++e) a[e] = (float)v[e];
            float s = 0;
            #pragma unroll
            for (int e = 0; e < 8; ++e) s += a[e];
            s += __shfl_xor(s, 1); s += __shfl_xor(s, 2); s += __shfl_xor(s, 4);
            const float mu = s * 0.015625f;
            float v2 = 0;
            #pragma unroll
            for (int e = 0; e < 8; ++e) { float d = a[e] - mu; v2 += d * d; }
            v2 += __shfl_xor(v2, 1); v2 += __shfl_xor(v2, 2); v2 += __shfl_xor(v2, 4);
            const float rs = rsqrtf(v2 * 0.015625f + 1e-5f);
            f32x4 g0 = *(const f32x4*)(gamma + c), g1 = *(const f32x4*)(gamma + c + 4);
            f32x4 b0 = *(const f32x4*)(beta + c),  b1 = *(const f32x4*)(beta + c + 4);
            bf16x8 o;
            #pragma unroll
            for (int e = 0; e < 4; ++e) {
                o[e]     = (bf16)(((a[e]     - mu) * rs * g0[e] + b0[e]) * outScale);
                o[4 + e] = (bf16)(((a[4 + e] - mu) * rs * g1[e] + b1[e]) * outScale);
            }
            *(bf16x8*)(outp + ((size_t)bh * NPpad) * HD + c) = o;
        } else {
            bf16x8 z = {};
            for (int p = NP + owg - 1; p < NPpad; p += 7)
                *(bf16x8*)(outp + ((size_t)bh * NPpad + p) * HD + c) = z;
        }
        return;
    }

    const int tp = task / (OH * CH);
    const int r2 = task % (OH * CH);
    const int oh = r2 / CH;
    const int ow = (r2 % CH) * 8 + owg;
    const bool active = (ow < OW);

    float acc0[8] = {}, acc1[8] = {};
    #pragma unroll
    for (int pl = 0; pl < 4; ++pl) {
        const int it = 2 * tp - 1 + pl;
        if (it < 0 || it >= TT) continue;
        #pragma unroll
        for (int dh = 0; dh < 3; ++dh) {
            int rowh;
            if constexpr (COMPACT) {
                const int hi = 3 * oh + dh - 1;
                if (hi < 0) continue;
                rowh = 1 + it * 400 + hi * 20;
            } else {
                const int ih = oh * S + dh - 1;
                if (ih < 0 || ih >= HH) continue;
                rowh = 1 + (it * HH + ih) * WW;
            }
            #pragma unroll
            for (int dw = 0; dw < 3; ++dw) {
                int rowoff;
                bool ok;
                if constexpr (COMPACT) {
                    const int wi = 3 * ow + dw - 1;
                    ok = active && (wi >= 0);
                    rowoff = rowh + wi;
                } else {
                    const int iw = ow * S + dw - 1;
                    ok = active && (iw >= 0);
                    rowoff = rowh + iw;
                }
                if (ok) {
                    bf16x8 v = *(const bf16x8*)(P + pbase + (size_t)rowoff * SRCSTRIDE);
                    float fv[8];
                    #pragma unroll
                    for (int e = 0; e < 8; ++e) fv[e] = (float)v[e];
                    if (pl <= 2) {
                        const float* wp = wt + ((pl * 3 + dh) * 3 + dw) * 64 + c;
                        f32x4 w0 = *(const f32x4*)wp, w1 = *(const f32x4*)(wp + 4);
                        #pragma unroll
                        for (int e = 0; e < 4; ++e) {
                            acc0[e]     += w0[e] * fv[e];
                            acc0[4 + e] += w1[e] * fv[4 + e];
                        }
                    }
                    if (pl >= 1) {
                        const float* wp = wt + (((pl - 1) * 3 + dh) * 3 + dw) * 64 + c;
                        f32x4 w0 = *(const f32x4*)wp, w1 = *(const f32x4*)(wp + 4);
                        #pragma unroll
                        for (int e = 0; e < 4; ++e) {
                            acc1[e]     += w0[e] * fv[e];
                            acc1[4 + e] += w1[e] * fv[4 + e];
                        }
                    }
                }
            }
        }
    }
    f32x4 g0 = *(const f32x4*)(gamma + c), g1 = *(const f32x4*)(gamma + c + 4);
    f32x4 b0 = *(const f32x4*)(beta + c),  b1 = *(const f32x4*)(beta + c + 4);
    #pragma unroll
    for (int half = 0; half < 2; ++half) {
        float* acc = half ? acc1 : acc0;
        float s = 0;
        #pragma unroll
        for (int e = 0; e < 8; ++e) s += acc[e];
        s += __shfl_xor(s, 1); s += __shfl_xor(s, 2); s += __shfl_xor(s, 4);
        const float mu = s * 0.015625f;
        float v2 = 0;
        #pragma unroll
        for (int e = 0; e < 8; ++e) { float d = acc[e] - mu; v2 += d * d; }
        v2 += __shfl_xor(v2, 1); v2 += __shfl_xor(v2, 2); v2 += __shfl_xor(v2, 4);
        const float rs = rsqrtf(v2 * 0.015625f + 1e-5f);
        if (active) {
            bf16x8 o;
            #pragma unroll
            for (int e = 0; e < 4; ++e) {
                o[e]     = (bf16)(((acc[e]     - mu) * rs * g0[e] + b0[e]) * outScale);
                o[4 + e] = (bf16)(((acc[4 + e] - mu) * rs * g1[e] + b1[e]) * outScale);
            }
            const int p = 1 + ((2 * tp + half) * OH + oh) * OW + ow;
            *(bf16x8*)(outp + ((size_t)bh * NPpad + p) * HD + c) = o;
        }
    }
}

// ---------------- merged pools: q quad (1368 blks) + k (696) + v (696) ----------------
__global__ __launch_bounds__(256) void pools_all(const bf16* __restrict__ tmpq,
                                                 const bf16* __restrict__ tmpkv,
                                                 const float* __restrict__ wt,
                                                 const float* __restrict__ gq, const float* __restrict__ bq,
                                                 const float* __restrict__ gk, const float* __restrict__ bk,
                                                 const float* __restrict__ gv, const float* __restrict__ bv,
                                                 bf16* __restrict__ qn, bf16* __restrict__ kn,
                                                 bf16* __restrict__ vnb) {
    const int w = threadIdx.x >> 6, lane = threadIdx.x & 63;
    const int bid = blockIdx.x;
    if (bid < 1368) {
        const int gw = xcd_remap(bid, 1368) * 4 + w;        // 96 bh x 57 tasks
        pool_q4(gw, lane, tmpq, wt, gq, bq, qn);
    } else if (bid < 2064) {
        const int gw = xcd_remap(bid - 1368, 696) * 4 + w;  // 96 bh x 29 tasks
        pool_body2<4, 7, 7, 1, NK, NKP, 1536, true>(gw, lane, tmpkv, wt + 1728, gk, bk, kn, 1.0f);
    } else {
        const int gw = xcd_remap(bid - 2064, 696) * 4 + w;
        pool_body2<4, 7, 7, 1, NK, NKP, 1536, true>(gw, lane, tmpkv + 768, wt + 3456, gv, bv, vnb, 1.0f);
    }
}

// ---------------- flash attention, fixed-max softmax (r13, unchanged) ----------------
__global__ __launch_bounds__(256) void attn_kernel(const bf16* __restrict__ qn,
                                                   const bf16* __restrict__ kn,
                                                   const bf16* __restrict__ vn,
                                                   bf16* __restrict__ ob,
                                                   const float* __restrict__ Mptr) {
    __shared__ bf16 Kl[2][32][72];
    __shared__ bf16 Vt[2][64][40];
    __shared__ bf16 Pl[4][16][40];

    const int tid = threadIdx.x, l = tid & 63, w = tid >> 6;
    const int li = l & 15, lg = l >> 4;
    const int wgid = xcd_remap(blockIdx.x, gridDim.x);
    const int bh = wgid / 25;
    const int b = bh / NH, head = bh % NH;
    const int qbase = (wgid % 25) * 64 + w * 16;
    const float M = Mptr[0];

    const bf16* qp = qn + ((size_t)bh * NQP + qbase + li) * HD + lg * 8;
    const bf16x8 aq0 = *(const bf16x8*)qp;
    const bf16x8 aq1 = *(const bf16x8*)(qp + 32);

    const int srow = tid >> 3, scol = (tid & 7) * 8;
    const int sj = tid & 31, sd8 = tid >> 5;
    const bf16* kbase = kn + (size_t)bh * NKP * HD;
    const bf16* vbase = vn + (size_t)bh * NKP * HD;

    u32x4 kv = *(const u32x4*)(kbase + srow * HD + scol);
    u32x4 vv = *(const u32x4*)(vbase + sj * HD + sd8 * 8);
    *(u32x4*)&Kl[0][srow][scol] = kv;
    {
        bf16x8 t = __builtin_bit_cast(bf16x8, vv);
        #pragma unroll
        for (int e = 0; e < 8; ++e) Vt[0][sd8 * 8 + e][sj] = t[e];
    }

    f32x4 oacc[4] = {};
    float lpart[4] = {0.f, 0.f, 0.f, 0.f};

    for (int kt = 0; kt < 13; ++kt) {
        const int cur = kt & 1;
        if (kt < 12) {
            kv = *(const u32x4*)(kbase + (kt + 1) * 32 * HD + srow * HD + scol);
            vv = *(const u32x4*)(vbase + (kt + 1) * 32 * HD + sj * HD + sd8 * 8);
        }
        __syncthreads();

        f32x4 c0 = {}, c1 = {};
        const bf16x8 b00 = *(const bf16x8*)&Kl[cur][li][lg * 8];
        const bf16x8 b01 = *(const bf16x8*)&Kl[cur][li][32 + lg * 8];
        const bf16x8 b10 = *(const bf16x8*)&Kl[cur][16 + li][lg * 8];
        const bf16x8 b11 = *(const bf16x8*)&Kl[cur][16 + li][32 + lg * 8];
        __builtin_amdgcn_s_setprio(1);
        c0 = MFMA16(aq0, b00, c0); c0 = MFMA16(aq1, b01, c0);
        c1 = MFMA16(aq0, b10, c1); c1 = MFMA16(aq1, b11, c1);
        __builtin_amdgcn_s_setprio(0);

        float p0[4], p1[4];
        #pragma unroll
        for (int r = 0; r < 4; ++r) {
            p0[r] = __expf(c0[r] - M);
            p1[r] = __expf(c1[r] - M);
        }
        if (kt == 12) {
            const bool m0 = (384 + li) >= NK;
            #pragma unroll
            for (int r = 0; r < 4; ++r) { if (m0) p0[r] = 0.f; p1[r] = 0.f; }
        }
        #pragma unroll
        for (int r = 0; r < 4; ++r) {
            lpart[r] += p0[r] + p1[r];
            Pl[w][lg * 4 + r][li]      = (bf16)p0[r];
            Pl[w][lg * 4 + r][16 + li] = (bf16)p1[r];
        }
        const bf16x8 ap = *(const bf16x8*)&Pl[w][li][lg * 8];
        __builtin_amdgcn_s_setprio(1);
        #pragma unroll
        for (int dg = 0; dg < 4; ++dg) {
            const bf16x8 bv = *(const bf16x8*)&Vt[cur][dg * 16 + li][lg * 8];
            oacc[dg] = MFMA16(ap, bv, oacc[dg]);
        }
        __builtin_amdgcn_s_setprio(0);

        if (kt < 12) {
            const int nxt = cur ^ 1;
            *(u32x4*)&Kl[nxt][srow][scol] = kv;
            bf16x8 t = __builtin_bit_cast(bf16x8, vv);
            #pragma unroll
            for (int e = 0; e < 8; ++e) Vt[nxt][sd8 * 8 + e][sj] = t[e];
        }
    }
    #pragma unroll
    for (int r = 0; r < 4; ++r) {
        float lsum = lpart[r];
        lsum += __shfl_xor(lsum, 1);
        lsum += __shfl_xor(lsum, 2);
        lsum += __shfl_xor(lsum, 4);
        lsum += __shfl_xor(lsum, 8);
        const int q = qbase + lg * 4 + r;
        if (q < NQ) {
            const float inv = 1.f / lsum;
            const size_t off = ((size_t)(b * NQ + q)) * CC + head * HD;
            #pragma unroll
            for (int dg = 0; dg < 4; ++dg)
                ob[off + dg * 16 + li] = (bf16)(oacc[dg][r] * inv);
        }
    }
}

// ---------------- launcher ----------------
extern "C" void kernel_launch(void* const* d_in, const int* in_sizes, int n_in,
                              void* d_out, int out_size, void* d_ws, size_t ws_size,
                              hipStream_t stream) {
    const float* x     = (const float*)d_in[0];
    const float* Wq    = (const float*)d_in[1];
    const float* Wk    = (const float*)d_in[2];
    const float* Wv    = (const float*)d_in[3];
    const float* Wproj = (const float*)d_in[4];
    const float* bproj = (const float*)d_in[5];
    const float* pqw   = (const float*)d_in[6];
    const float* pkw   = (const float*)d_in[7];
    const float* pvw   = (const float*)d_in[8];
    const float* gq    = (const float*)d_in[9];
    const float* bq    = (const float*)d_in[10];
    const float* gk    = (const float*)d_in[11];
    const float* bk    = (const float*)d_in[12];
    const float* gv    = (const float*)d_in[13];
    const float* bv    = (const float*)d_in[14];

    if (ws_size < 364000000ULL) return;
    char* ws = (char*)d_ws;
    bf16* xb    = (bf16*)(ws);               // [50304][768]
    bf16* wqkv  = (bf16*)(ws + 77266944);    // [2304][768] + wpb contiguous
    bf16* wpb   = (bf16*)(ws + 80805888);    // [768][768]
    bf16* tmpq  = (bf16*)(ws + 81985536);    // [50304][768]
    bf16* tmpkv = (bf16*)(ws + 159252480);   // [25856][1536]
    bf16* qn    = (bf16*)(ws + 238682112);   // [96][1600][64]
    bf16* kn    = (bf16*)(ws + 258342912);   // [96][416][64]
    bf16* vnb   = (bf16*)(ws + 263454720);   // [96][416][64]
    bf16* ob    = (bf16*)(ws + 268566528);   // [12672][768]
    float* wt   = (float*)(ws + 288030720);  // [3][27][64] f32
    float* Mb   = (float*)(ws + 288051456);  // [1]

    (void)hipFuncSetAttribute((const void*)gemmU,
                              hipFuncAttributeMaxDynamicSharedMemorySize, 131072);
    (void)hipFuncSetAttribute((const void*)gemmF,
                              hipFuncAttributeMaxDynamicSharedMemorySize, 98304);

    prep_all<<<6422, 256, 0, stream>>>(x, Wq, Wk, Wv, Wproj, pqw, pkw, pvw,
                                       gq, bq, gk, bk, xb, wqkv, wt, Mb);

    gemmU<<<1197, 512, 131072, stream>>>(xb, wqkv, tmpq, tmpkv);

    pools_all<<<2760, 256, 0, stream>>>(tmpq, tmpkv, wt, gq, bq, gk, bk, gv, bv,
                                        qn, kn, vnb);

    attn_kernel<<<2400, 256, 0, stream>>>(qn, kn, vnb, ob, Mb);

    gemmF<<<50 * 6, 512, 98304, stream>>>(ob, wpb, (float*)d_out, bproj, 6, MO, MOP);
}

// Round 16
// 320.018 us; speedup vs baseline: 1.1667x; 1.0105x over previous
//
#include <hip/hip_runtime.h>

using bf16   = __bf16;
using bf16x4 = __attribute__((ext_vector_type(4))) __bf16;
using bf16x8 = __attribute__((ext_vector_type(8))) __bf16;
using f32x4  = __attribute__((ext_vector_type(4))) float;
using u32x4  = __attribute__((ext_vector_type(4))) unsigned int;

#define MFMA16(a,b,c) __builtin_amdgcn_mfma_f32_16x16x32_bf16((a),(b),(c),0,0,0)

__device__ inline void glds16(const void* g, void* l) {
    __builtin_amdgcn_global_load_lds(
        (__attribute__((address_space(1))) void*)(const_cast<void*>(g)),
        (__attribute__((address_space(3))) void*)(l), 16, 0, 0);
}

// bijective XCD-chunked remap (m204)
__device__ inline int xcd_remap(int bid, int nwg) {
    const int xcd = bid & 7, loc = bid >> 3;
    const int q8 = nwg >> 3, r8 = nwg & 7;
    return (xcd < r8 ? xcd * (q8 + 1) : r8 * (q8 + 1) + (xcd - r8) * q8) + loc;
}

// ---------------- constants ----------------
constexpr int CB   = 8;
constexpr int NH   = 12;
constexpr int CC   = 768;
constexpr int HD   = 64;
constexpr int TT   = 8, HH = 28, WW = 28;
constexpr int NTOK = TT*HH*WW + 1;      // 6273
constexpr int MX   = CB*NTOK;           // 50184
constexpr int MXP  = 50304;
constexpr int NQ   = 1569, NQP = 1664;  // padded to 13*128 for attn QBLK=128
constexpr int NK   = 393,  NKP = 416;
constexpr int MO   = CB*NQ;             // 12552
constexpr int MOP  = 12672;
constexpr int CTOK = 1 + TT*20*20;      // 3201
constexpr int MKV  = CB*CTOK;           // 25608
constexpr int MKVP = 25856;

// ---------------- merged prep: x-cast + weight cast + wt transpose + bound ----------------
__global__ __launch_bounds__(256) void prep_all(const float* __restrict__ x,
                                                const float* __restrict__ Wq, const float* __restrict__ Wk,
                                                const float* __restrict__ Wv, const float* __restrict__ Wp,
                                                const float* __restrict__ pqw, const float* __restrict__ pkw,
                                                const float* __restrict__ pvw,
                                                const float* __restrict__ gq, const float* __restrict__ bq,
                                                const float* __restrict__ gk, const float* __restrict__ bk,
                                                bf16* __restrict__ xb, bf16* __restrict__ wdst,
                                                float* __restrict__ wt, float* __restrict__ Mb) {
    constexpr int WSZ = 589824;
    const int bid = blockIdx.x, tid = threadIdx.x;
    if (bid < 4096) {
        const int nvalid = MX * CC, ntotal = MXP * CC;
        int i = (bid * 256 + tid) * 4;
        const int stride = 4096 * 256 * 4;
        for (; i < ntotal; i += stride) {
            bf16x4 o;
            if (i + 3 < nvalid) {
                f32x4 v = *(const f32x4*)(x + i);
                #pragma unroll
                for (int e = 0; e < 4; ++e) o[e] = (bf16)v[e];
            } else {
                #pragma unroll
                for (int e = 0; e < 4; ++e) {
                    int k = i + e;
                    o[e] = (bf16)((k < nvalid) ? x[k] : 0.f);
                }
            }
            *(bf16x4*)(xb + i) = o;
        }
    } else if (bid < 6400) {
        int i = ((bid - 4096) * 256 + tid) * 4;
        const int setn = i / WSZ, j = i % WSZ;
        const float* src = (setn == 0) ? Wq : (setn == 1) ? Wk : (setn == 2) ? Wv : Wp;
        f32x4 v = *(const f32x4*)(src + j);
        bf16x4 o;
        #pragma unroll
        for (int e = 0; e < 4; ++e) o[e] = (bf16)v[e];
        *(bf16x4*)(wdst + i) = o;
    } else if (bid < 6421) {
        int i = (bid - 6400) * 256 + tid;
        if (i < 3 * 1728) {
            int setn = i / 1728, j = i % 1728;
            const float* src = (setn == 0) ? pqw : (setn == 1) ? pkw : pvw;
            int tap = j / 64, c = j % 64;
            wt[i] = src[c * 27 + tap];
        }
    } else if (tid < 64) {
        const int c = tid;
        float mgq = fabsf(gq[c]), sbq = bq[c] * bq[c];
        float mgk = fabsf(gk[c]), sbk = bk[c] * bk[c];
        #pragma unroll
        for (int m = 1; m < 64; m <<= 1) {
            mgq = fmaxf(mgq, __shfl_xor(mgq, m)); sbq += __shfl_xor(sbq, m);
            mgk = fmaxf(mgk, __shfl_xor(mgk, m)); sbk += __shfl_xor(sbk, m);
        }
        if (c == 0) {
            const float Bq = 8.f * mgq + sqrtf(sbq);
            const float Bk = 8.f * mgk + sqrtf(sbk);
            Mb[0] = 0.125f * Bq * Bk;
        }
    }
}

// ---------------- unified Q + gathered-KV projection GEMM (r13, unchanged) ----------------
__global__ __launch_bounds__(512, 2) void gemmU(const bf16* __restrict__ xb,
                                                const bf16* __restrict__ wqkv,
                                                bf16* __restrict__ tmpq,
                                                bf16* __restrict__ tmpkv) {
    extern __shared__ char lds[];
    const int wgid = xcd_remap(blockIdx.x, gridDim.x);   // 1197

    const int tid = threadIdx.x, lane = tid & 63, w = tid >> 6;
    const int li = lane & 15, lg = lane >> 4;
    const int wr = w >> 2, wc = w & 3;
    const int lr  = lane >> 3;
    const int lsw = ((lane & 7) ^ lr) << 3;

    const bool isQ = wgid < 591;
    int bm, bn, Mv, ldc;
    const bf16* Bb;
    bf16* C;
    if (isQ) { bm = wgid / 3;        bn = wgid % 3;        Mv = MXP;  ldc = 768;
               Bb = wqkv + (size_t)bn * 256 * 768;               C = tmpq; }
    else     { int t = wgid - 591;   bm = t / 6; bn = t % 6; Mv = MKVP; ldc = 1536;
               Bb = wqkv + (size_t)(768 + bn * 256) * 768;       C = tmpkv; }

    const bf16* abase[4];
    const bf16* bbase[4];
    #pragma unroll
    for (int h_ = 0; h_ < 4; ++h_) {
        int gr = bm * 256 + h_ * 64 + w * 8 + lr;
        size_t orig;
        if (isQ) {
            if (gr > MXP - 1) gr = MXP - 1;
            orig = (size_t)gr;
        } else {
            if (gr > MKV - 1) gr = MKV - 1;
            const unsigned b = (unsigned)gr / 3201u;
            const unsigned p = (unsigned)gr % 3201u;
            if (p == 0) orig = (size_t)b * NTOK;
            else {
                const unsigned q  = p - 1;
                const unsigned t2 = q / 400u, rem = q % 400u;
                const unsigned hi = rem / 20u, wi = rem % 20u;
                const int ih = 4 * (int)((hi + 1) / 3) + (int)((hi + 1) % 3) - 1;
                const int iw = 4 * (int)((wi + 1) / 3) + (int)((wi + 1) % 3) - 1;
                orig = (size_t)b * NTOK + 1 + ((size_t)t2 * HH + ih) * WW + iw;
            }
        }
        abase[h_] = xb + orig * 768 + lsw;
        bbase[h_] = Bb + (size_t)(h_ * 64 + w * 8 + lr) * 768 + lsw;
    }

    const int sw_  = (li & 7) << 4;
    const int swc0 = (lg * 16) ^ sw_;
    const int swc1 = (64 | (lg * 16)) ^ sw_;

#define STAGE_T(Tt, buf) do {                                                        \
        char* d_ = lds + (buf) * 65536;                                              \
        _Pragma("unroll")                                                            \
        for (int h_ = 0; h_ < 4; ++h_)                                               \
            glds16(abase[h_] + (size_t)(Tt) * 64, d_ + (h_ * 64 + w * 8) * 128);     \
        _Pragma("unroll")                                                            \
        for (int h_ = 0; h_ < 4; ++h_)                                               \
            glds16(bbase[h_] + (size_t)(Tt) * 64, d_ + 32768 + (h_ * 64 + w * 8) * 128); \
    } while (0)

    f32x4 acc[8][4] = {};
    bf16x8 aF[8], bF[4];

#define READ_K(sw)                                                                   \
    _Pragma("unroll") for (int mf = 0; mf < 8; ++mf)                                 \
        aF[mf] = *(const bf16x8*)(bufA + (size_t)(wr * 128 + mf * 16 + li) * 128 + (sw)); \
    _Pragma("unroll") for (int nf = 0; nf < 4; ++nf)                                 \
        bF[nf] = *(const bf16x8*)(bufB + (size_t)(wc * 64 + nf * 16 + li) * 128 + (sw));

#define MFMA_K()                                                                     \
    _Pragma("unroll") for (int mf = 0; mf < 8; ++mf)                                 \
    _Pragma("unroll") for (int nf = 0; nf < 4; ++nf)                                 \
        acc[mf][nf] = MFMA16(aF[mf], bF[nf], acc[mf][nf]);

    STAGE_T(0, 0);
    STAGE_T(1, 1);
    asm volatile("s_waitcnt vmcnt(8)" ::: "memory");
    __builtin_amdgcn_s_barrier();
    __builtin_amdgcn_sched_barrier(0);

    #pragma unroll
    for (int T = 0; T < 12; ++T) {
        const char* bufA = lds + (T & 1) * 65536;
        const char* bufB = bufA + 32768;
        if (T >= 1 && T < 11) STAGE_T(T + 1, (T + 1) & 1);
        READ_K(swc0);
        __builtin_amdgcn_s_setprio(1);
        MFMA_K();
        __builtin_amdgcn_s_setprio(0);
        READ_K(swc1);
        __builtin_amdgcn_s_setprio(1);
        MFMA_K();
        __builtin_amdgcn_s_setprio(0);
        asm volatile("s_waitcnt lgkmcnt(0)" ::: "memory");
        if (T < 11) asm volatile("s_waitcnt vmcnt(0)" ::: "memory");
        __builtin_amdgcn_s_barrier();
        __builtin_amdgcn_sched_barrier(0);
    }
#undef STAGE_T
#undef READ_K
#undef MFMA_K

    #pragma unroll
    for (int mf = 0; mf < 8; ++mf) {
        const int row0 = bm * 256 + wr * 128 + mf * 16 + lg * 4;
        #pragma unroll
        for (int nf = 0; nf < 4; ++nf) {
            const int col = bn * 256 + wc * 64 + nf * 16 + li;
            #pragma unroll
            for (int r = 0; r < 4; ++r) {
                const int row = row0 + r;
                if (row < Mv)
                    C[(size_t)row * ldc + col] = (bf16)acc[mf][nf][r];
            }
        }
    }
}

// ---------------- final projection GEMM: 256x128 tile (r13, unchanged) ----------------
__global__ __launch_bounds__(512, 2) void gemmF(const bf16* __restrict__ A,
                                                const bf16* __restrict__ Bw,
                                                float* __restrict__ Cptr,
                                                const float* __restrict__ bias,
                                                int nbn, int Mvalid, int Aclamp) {
    extern __shared__ char lds[];
    const int wgid = xcd_remap(blockIdx.x, gridDim.x);
    const int bm = wgid / nbn, bn = wgid % nbn;

    const int tid = threadIdx.x, lane = tid & 63, w = tid >> 6;
    const int li = lane & 15, lg = lane >> 4;
    const int wr = w >> 2, wc = w & 3;
    const int lr  = lane >> 3;
    const int lsw = ((lane & 7) ^ lr) << 3;
    const bf16* Agp = A  + (size_t)bm * 256 * 768;
    const bf16* Bgp = Bw + (size_t)bn * 128 * 768;
    const int clampA = Aclamp - bm * 256;

    const int sw_  = (li & 7) << 4;
    const int swc0 = (lg * 16) ^ sw_;
    const int swc1 = (64 | (lg * 16)) ^ sw_;

#define STAGE_T(Tt, buf) do {                                                        \
        char* d_ = lds + (buf) * 49152;                                              \
        _Pragma("unroll")                                                            \
        for (int h_ = 0; h_ < 4; ++h_) {                                             \
            const int r0_ = h_ * 64 + w * 8;                                         \
            int gr_ = r0_ + lr; if (gr_ >= clampA) gr_ = clampA - 1;                 \
            glds16(Agp + (size_t)gr_ * 768 + (Tt) * 64 + lsw, d_ + r0_ * 128);       \
        }                                                                            \
        _Pragma("unroll")                                                            \
        for (int h_ = 0; h_ < 2; ++h_) {                                             \
            const int r0_ = h_ * 64 + w * 8;                                         \
            glds16(Bgp + (size_t)(r0_ + lr) * 768 + (Tt) * 64 + lsw,                 \
                   d_ + 32768 + r0_ * 128);                                          \
        } } while (0)

    f32x4 acc[8][2] = {};
    bf16x8 aF[8], bF[2];

#define READ_K(sw)                                                                   \
    _Pragma("unroll") for (int mf = 0; mf < 8; ++mf)                                 \
        aF[mf] = *(const bf16x8*)(bufA + (size_t)(wr * 128 + mf * 16 + li) * 128 + (sw)); \
    _Pragma("unroll") for (int nf = 0; nf < 2; ++nf)                                 \
        bF[nf] = *(const bf16x8*)(bufB + (size_t)(wc * 32 + nf * 16 + li) * 128 + (sw));

#define MFMA_K()                                                                     \
    _Pragma("unroll") for (int mf = 0; mf < 8; ++mf)                                 \
    _Pragma("unroll") for (int nf = 0; nf < 2; ++nf)                                 \
        acc[mf][nf] = MFMA16(aF[mf], bF[nf], acc[mf][nf]);

    STAGE_T(0, 0);
    STAGE_T(1, 1);
    asm volatile("s_waitcnt vmcnt(6)" ::: "memory");
    __builtin_amdgcn_s_barrier();
    __builtin_amdgcn_sched_barrier(0);

    #pragma unroll
    for (int T = 0; T < 12; ++T) {
        const char* bufA = lds + (T & 1) * 49152;
        const char* bufB = bufA + 32768;
        if (T >= 1 && T < 11) STAGE_T(T + 1, (T + 1) & 1);
        READ_K(swc0);
        __builtin_amdgcn_s_setprio(1);
        MFMA_K();
        __builtin_amdgcn_s_setprio(0);
        READ_K(swc1);
        __builtin_amdgcn_s_setprio(1);
        MFMA_K();
        __builtin_amdgcn_s_setprio(0);
        asm volatile("s_waitcnt lgkmcnt(0)" ::: "memory");
        if (T < 11) asm volatile("s_waitcnt vmcnt(0)" ::: "memory");
        __builtin_amdgcn_s_barrier();
        __builtin_amdgcn_sched_barrier(0);
    }
#undef STAGE_T
#undef READ_K
#undef MFMA_K

    #pragma unroll
    for (int mf = 0; mf < 8; ++mf) {
        const int row0 = bm * 256 + wr * 128 + mf * 16 + lg * 4;
        #pragma unroll
        for (int nf = 0; nf < 2; ++nf) {
            const int col = bn * 128 + wc * 32 + nf * 16 + li;
            #pragma unroll
            for (int r = 0; r < 4; ++r) {
                const int row = row0 + r;
                if (row < Mvalid)
                    Cptr[(size_t)row * 768 + col] = acc[mf][nf][r] + bias[col];
            }
        }
    }
}

// ---------------- q-pool quad body (r15, unchanged semantics; NQP now 1664) ----------------
__device__ __forceinline__ void pool_q4(int gw, int lane,
                                        const bf16* __restrict__ P,
                                        const float* __restrict__ wt,
                                        const float* __restrict__ gamma,
                                        const float* __restrict__ beta,
                                        bf16* __restrict__ outp) {
    constexpr int TASKS = 57;
    const int bh = gw / TASKS, task = gw % TASKS;
    const int b = bh / NH, head = bh % NH;
    const int owp = lane >> 3, cg = lane & 7, c = cg * 8;
    const size_t pbase = (size_t)b * NTOK * 768 + head * HD + c;

    if (task == TASKS - 1) {
        if (owp == 0) {
            bf16x8 v = *(const bf16x8*)(P + pbase);
            float a[8];
            #pragma unroll
            for (int e = 0; e < 8; ++e) a[e] = (float)v[e];
            float s = 0;
            #pragma unroll
            for (int e = 0; e < 8; ++e) s += a[e];
            s += __shfl_xor(s, 1); s += __shfl_xor(s, 2); s += __shfl_xor(s, 4);
            const float mu = s * 0.015625f;
            float v2 = 0;
            #pragma unroll
            for (int e = 0; e < 8; ++e) { float d = a[e] - mu; v2 += d * d; }
            v2 += __shfl_xor(v2, 1); v2 += __shfl_xor(v2, 2); v2 += __shfl_xor(v2, 4);
            const float rs = rsqrtf(v2 * 0.015625f + 1e-5f);
            f32x4 g0 = *(const f32x4*)(gamma + c), g1 = *(const f32x4*)(gamma + c + 4);
            f32x4 b0 = *(const f32x4*)(beta + c),  b1 = *(const f32x4*)(beta + c + 4);
            bf16x8 o;
            #pragma unroll
            for (int e = 0; e < 4; ++e) {
                o[e]     = (bf16)(((a[e]     - mu) * rs * g0[e] + b0[e]) * 0.125f);
                o[4 + e] = (bf16)(((a[4 + e] - mu) * rs * g1[e] + b1[e]) * 0.125f);
            }
            *(bf16x8*)(outp + ((size_t)bh * NQP) * HD + c) = o;
        } else {
            bf16x8 z = {};
            for (int p = NQ + owp - 1; p < NQP; p += 7)
                *(bf16x8*)(outp + ((size_t)bh * NQP + p) * HD + c) = z;
        }
        return;
    }

    const int tp = task / 14, oh = task % 14;
    const bool active = (owp < 7);

    float a00[8] = {}, a01[8] = {}, a10[8] = {}, a11[8] = {};
    #pragma unroll
    for (int pl = 0; pl < 4; ++pl) {
        const int it = 2 * tp - 1 + pl;
        if (it < 0 || it >= TT) continue;
        #pragma unroll
        for (int dh = 0; dh < 3; ++dh) {
            const int ih = 2 * oh + dh - 1;
            if (ih < 0 || ih >= HH) continue;
            const int rowh = 1 + (it * HH + ih) * WW;
            #pragma unroll
            for (int du = 0; du < 5; ++du) {
                const int iw = 4 * owp - 1 + du;
                if (active && iw >= 0 && iw < WW) {
                    bf16x8 v = *(const bf16x8*)(P + pbase + (size_t)(rowh + iw) * 768);
                    float fv[8];
                    #pragma unroll
                    for (int e = 0; e < 8; ++e) fv[e] = (float)v[e];
#define TAP(ACC, DT, DW) do {                                                        \
        const float* wp_ = wt + (((DT) * 3 + dh) * 3 + (DW)) * 64 + c;               \
        f32x4 w0_ = *(const f32x4*)wp_, w1_ = *(const f32x4*)(wp_ + 4);              \
        _Pragma("unroll")                                                            \
        for (int e = 0; e < 4; ++e) {                                                \
            ACC[e]     += w0_[e] * fv[e];                                            \
            ACC[4 + e] += w1_[e] * fv[4 + e];                                        \
        } } while (0)
                    if (du <= 2) {
                        if (pl <= 2) TAP(a00, pl,     du);
                        if (pl >= 1) TAP(a10, pl - 1, du);
                    }
                    if (du >= 2) {
                        if (pl <= 2) TAP(a01, pl,     du - 2);
                        if (pl >= 1) TAP(a11, pl - 1, du - 2);
                    }
#undef TAP
                }
            }
        }
    }
    f32x4 g0 = *(const f32x4*)(gamma + c), g1 = *(const f32x4*)(gamma + c + 4);
    f32x4 b0 = *(const f32x4*)(beta + c),  b1 = *(const f32x4*)(beta + c + 4);
#define LNSTORE(ACC, HT, HW) do {                                                    \
        float s_ = 0;                                                                \
        _Pragma("unroll") for (int e = 0; e < 8; ++e) s_ += ACC[e];                  \
        s_ += __shfl_xor(s_, 1); s_ += __shfl_xor(s_, 2); s_ += __shfl_xor(s_, 4);   \
        const float mu_ = s_ * 0.015625f;                                            \
        float v2_ = 0;                                                               \
        _Pragma("unroll") for (int e = 0; e < 8; ++e) {                              \
            float d_ = ACC[e] - mu_; v2_ += d_ * d_; }                               \
        v2_ += __shfl_xor(v2_, 1); v2_ += __shfl_xor(v2_, 2); v2_ += __shfl_xor(v2_, 4); \
        const float rs_ = rsqrtf(v2_ * 0.015625f + 1e-5f);                           \
        if (active) {                                                                \
            bf16x8 o_;                                                               \
            _Pragma("unroll") for (int e = 0; e < 4; ++e) {                          \
                o_[e]     = (bf16)(((ACC[e]     - mu_) * rs_ * g0[e] + b0[e]) * 0.125f); \
                o_[4 + e] = (bf16)(((ACC[4 + e] - mu_) * rs_ * g1[e] + b1[e]) * 0.125f); \
            }                                                                        \
            const int p_ = 1 + ((2 * tp + (HT)) * 14 + oh) * 14 + (2 * owp + (HW));  \
            *(bf16x8*)(outp + ((size_t)bh * NQP + p_) * HD + c) = o_;                \
        } } while (0)
    LNSTORE(a00, 0, 0);
    LNSTORE(a01, 0, 1);
    LNSTORE(a10, 1, 0);
    LNSTORE(a11, 1, 1);
#undef LNSTORE
}

// ---------------- k/v pool body: 2 consecutive t outputs per lane (r14, unchanged) ----------------
template<int S, int OH, int OW, int CH, int NP, int NPpad, int SRCSTRIDE, bool COMPACT>
__device__ __forceinline__ void pool_body2(int gw, int lane,
                                           const bf16* __restrict__ P,
                                           const float* __restrict__ wt,
                                           const float* __restrict__ gamma,
                                           const float* __restrict__ beta,
                                           bf16* __restrict__ outp,
                                           float outScale) {
    constexpr int TASKS = 4 * OH * CH + 1;
    const int bh = gw / TASKS, task = gw % TASKS;
    const int b = bh / NH, head = bh % NH;
    const int owg = lane >> 3, cg = lane & 7, c = cg * 8;
    const size_t rowbase = COMPACT ? (size_t)b * CTOK : (size_t)b * NTOK;
    const size_t pbase = rowbase * SRCSTRIDE + head * HD + c;

    if (task == TASKS - 1) {
        if (owg == 0) {
            bf16x8 v = *(const bf16x8*)(P + pbase);
            float a[8];
            #pragma unroll
            for (int e = 0; e < 8; ++e) a[e] = (float)v[e];
            float s = 0;
            #pragma unroll
            for (int e = 0; e < 8; ++e) s += a[e];
            s += __shfl_xor(s, 1); s += __shfl_xor(s, 2); s += __shfl_xor(s, 4);
            const float mu = s * 0.015625f;
            float v2 = 0;
            #pragma unroll
            for (int e = 0; e < 8; ++e) { float d = a[e] - mu; v2 += d * d; }
            v2 += __shfl_xor(v2, 1); v2 += __shfl_xor(v2, 2); v2 += __shfl_xor(v2, 4);
            const float rs = rsqrtf(v2 * 0.015625f + 1e-5f);
            f32x4 g0 = *(const f32x4*)(gamma + c), g1 = *(const f32x4*)(gamma + c + 4);
            f32x4 b0 = *(const f32x4*)(beta + c),  b1 = *(const f32x4*)(beta + c + 4);
            bf16x8 o;
            #pragma unroll
            for (int e = 0; e < 4; ++e) {
                o[e]     = (bf16)(((a[e]     - mu) * rs * g0[e] + b0[e]) * outScale);
                o[4 + e] = (bf16)(((a[4 + e] - mu) * rs * g1[e] + b1[e]) * outScale);
            }
            *(bf16x8*)(outp + ((size_t)bh * NPpad) * HD + c) = o;
        } else {
            bf16x8 z = {};
            for (int p = NP + owg - 1; p < NPpad; p += 7)
                *(bf16x8*)(outp + ((size_t)bh * NPpad + p) * HD + c) = z;
        }
        return;
    }

    const int tp = task / (OH * CH);
    const int r2 = task % (OH * CH);
    const int oh = r2 / CH;
    const int ow = (r2 % CH) * 8 + owg;
    const bool active = (ow < OW);

    float acc0[8] = {}, acc1[8] = {};
    #pragma unroll
    for (int pl = 0; pl < 4; ++pl) {
        const int it = 2 * tp - 1 + pl;
        if (it < 0 || it >= TT) continue;
        #pragma unroll
        for (int dh = 0; dh < 3; ++dh) {
            int rowh;
            if constexpr (COMPACT) {
                const int hi = 3 * oh + dh - 1;
                if (hi < 0) continue;
                rowh = 1 + it * 400 + hi * 20;
            } else {
                const int ih = oh * S + dh - 1;
                if (ih < 0 || ih >= HH) continue;
                rowh = 1 + (it * HH + ih) * WW;
            }
            #pragma unroll
            for (int dw = 0; dw < 3; ++dw) {
                int rowoff;
                bool ok;
                if constexpr (COMPACT) {
                    const int wi = 3 * ow + dw - 1;
                    ok = active && (wi >= 0);
                    rowoff = rowh + wi;
                } else {
                    const int iw = ow * S + dw - 1;
                    ok = active && (iw >= 0);
                    rowoff = rowh + iw;
                }
                if (ok) {
                    bf16x8 v = *(const bf16x8*)(P + pbase + (size_t)rowoff * SRCSTRIDE);
                    float fv[8];
                    #pragma unroll
                    for (int e = 0; e < 8; ++e) fv[e] = (float)v[e];
                    if (pl <= 2) {
                        const float* wp = wt + ((pl * 3 + dh) * 3 + dw) * 64 + c;
                        f32x4 w0 = *(const f32x4*)wp, w1 = *(const f32x4*)(wp + 4);
                        #pragma unroll
                        for (int e = 0; e < 4; ++e) {
                            acc0[e]     += w0[e] * fv[e];
                            acc0[4 + e] += w1[e] * fv[4 + e];
                        }
                    }
                    if (pl >= 1) {
                        const float* wp = wt + (((pl - 1) * 3 + dh) * 3 + dw) * 64 + c;
                        f32x4 w0 = *(const f32x4*)wp, w1 = *(const f32x4*)(wp + 4);
                        #pragma unroll
                        for (int e = 0; e < 4; ++e) {
                            acc1[e]     += w0[e] * fv[e];
                            acc1[4 + e] += w1[e] * fv[4 + e];
                        }
                    }
                }
            }
        }
    }
    f32x4 g0 = *(const f32x4*)(gamma + c), g1 = *(const f32x4*)(gamma + c + 4);
    f32x4 b0 = *(const f32x4*)(beta + c),  b1 = *(const f32x4*)(beta + c + 4);
    #pragma unroll
    for (int half = 0; half < 2; ++half) {
        float* acc = half ? acc1 : acc0;
        float s = 0;
        #pragma unroll
        for (int e = 0; e < 8; ++e) s += acc[e];
        s += __shfl_xor(s, 1); s += __shfl_xor(s, 2); s += __shfl_xor(s, 4);
        const float mu = s * 0.015625f;
        float v2 = 0;
        #pragma unroll
        for (int e = 0; e < 8; ++e) { float d = acc[e] - mu; v2 += d * d; }
        v2 += __shfl_xor(v2, 1); v2 += __shfl_xor(v2, 2); v2 += __shfl_xor(v2, 4);
        const float rs = rsqrtf(v2 * 0.015625f + 1e-5f);
        if (active) {
            bf16x8 o;
            #pragma unroll
            for (int e = 0; e < 4; ++e) {
                o[e]     = (bf16)(((acc[e]     - mu) * rs * g0[e] + b0[e]) * outScale);
                o[4 + e] = (bf16)(((acc[4 + e] - mu) * rs * g1[e] + b1[e]) * outScale);
            }
            const int p = 1 + ((2 * tp + half) * OH + oh) * OW + ow;
            *(bf16x8*)(outp + ((size_t)bh * NPpad + p) * HD + c) = o;
        }
    }
}

// ---------------- merged pools: q quad (1368 blks) + k (696) + v (696) ----------------
__global__ __launch_bounds__(256) void pools_all(const bf16* __restrict__ tmpq,
                                                 const bf16* __restrict__ tmpkv,
                                                 const float* __restrict__ wt,
                                                 const float* __restrict__ gq, const float* __restrict__ bq,
                                                 const float* __restrict__ gk, const float* __restrict__ bk,
                                                 const float* __restrict__ gv, const float* __restrict__ bv,
                                                 bf16* __restrict__ qn, bf16* __restrict__ kn,
                                                 bf16* __restrict__ vnb) {
    const int w = threadIdx.x >> 6, lane = threadIdx.x & 63;
    const int bid = blockIdx.x;
    if (bid < 1368) {
        const int gw = xcd_remap(bid, 1368) * 4 + w;
        pool_q4(gw, lane, tmpq, wt, gq, bq, qn);
    } else if (bid < 2064) {
        const int gw = xcd_remap(bid - 1368, 696) * 4 + w;
        pool_body2<4, 7, 7, 1, NK, NKP, 1536, true>(gw, lane, tmpkv, wt + 1728, gk, bk, kn, 1.0f);
    } else {
        const int gw = xcd_remap(bid - 2064, 696) * 4 + w;
        pool_body2<4, 7, 7, 1, NK, NKP, 1536, true>(gw, lane, tmpkv + 768, wt + 3456, gv, bv, vnb, 1.0f);
    }
}

// ---------------- flash attention: 32 q-rows/wave (QBLK=128), fixed-max softmax ----------------
__global__ __launch_bounds__(256) void attn_kernel(const bf16* __restrict__ qn,
                                                   const bf16* __restrict__ kn,
                                                   const bf16* __restrict__ vn,
                                                   bf16* __restrict__ ob,
                                                   const float* __restrict__ Mptr) {
    __shared__ bf16 Kl[2][32][72];
    __shared__ bf16 Vt[2][64][40];
    __shared__ bf16 Pl[4][32][40];

    const int tid = threadIdx.x, l = tid & 63, w = tid >> 6;
    const int li = l & 15, lg = l >> 4;
    const int wgid = xcd_remap(blockIdx.x, gridDim.x);   // 96 bh x 13 qblocks
    const int bh = wgid / 13;
    const int b = bh / NH, head = bh % NH;
    const int qbase = (wgid % 13) * 128 + w * 32;
    const float M = Mptr[0];

    // two q fragments per wave (rows qbase+qf*16+li)
    bf16x8 aq[2][2];
    #pragma unroll
    for (int qf = 0; qf < 2; ++qf) {
        const bf16* qp = qn + ((size_t)bh * NQP + qbase + qf * 16 + li) * HD + lg * 8;
        aq[qf][0] = *(const bf16x8*)qp;
        aq[qf][1] = *(const bf16x8*)(qp + 32);
    }

    const int srow = tid >> 3, scol = (tid & 7) * 8;
    const int sj = tid & 31, sd8 = tid >> 5;
    const bf16* kbase = kn + (size_t)bh * NKP * HD;
    const bf16* vbase = vn + (size_t)bh * NKP * HD;

    u32x4 kv = *(const u32x4*)(kbase + srow * HD + scol);
    u32x4 vv = *(const u32x4*)(vbase + sj * HD + sd8 * 8);
    *(u32x4*)&Kl[0][srow][scol] = kv;
    {
        bf16x8 t = __builtin_bit_cast(bf16x8, vv);
        #pragma unroll
        for (int e = 0; e < 8; ++e) Vt[0][sd8 * 8 + e][sj] = t[e];
    }

    f32x4 oacc[2][4] = {};
    float lpart[2][4] = {};

    for (int kt = 0; kt < 13; ++kt) {
        const int cur = kt & 1;
        if (kt < 12) {
            kv = *(const u32x4*)(kbase + (kt + 1) * 32 * HD + srow * HD + scol);
            vv = *(const u32x4*)(vbase + (kt + 1) * 32 * HD + sj * HD + sd8 * 8);
        }
        __syncthreads();

        const bf16x8 b00 = *(const bf16x8*)&Kl[cur][li][lg * 8];
        const bf16x8 b01 = *(const bf16x8*)&Kl[cur][li][32 + lg * 8];
        const bf16x8 b10 = *(const bf16x8*)&Kl[cur][16 + li][lg * 8];
        const bf16x8 b11 = *(const bf16x8*)&Kl[cur][16 + li][32 + lg * 8];

        #pragma unroll
        for (int qf = 0; qf < 2; ++qf) {
            f32x4 c0 = {}, c1 = {};
            __builtin_amdgcn_s_setprio(1);
            c0 = MFMA16(aq[qf][0], b00, c0); c0 = MFMA16(aq[qf][1], b01, c0);
            c1 = MFMA16(aq[qf][0], b10, c1); c1 = MFMA16(aq[qf][1], b11, c1);
            __builtin_amdgcn_s_setprio(0);

            float p0[4], p1[4];
            #pragma unroll
            for (int r = 0; r < 4; ++r) {
                p0[r] = __expf(c0[r] - M);
                p1[r] = __expf(c1[r] - M);
            }
            if (kt == 12) {
                const bool m0 = (384 + li) >= NK;
                #pragma unroll
                for (int r = 0; r < 4; ++r) { if (m0) p0[r] = 0.f; p1[r] = 0.f; }
            }
            #pragma unroll
            for (int r = 0; r < 4; ++r) {
                lpart[qf][r] += p0[r] + p1[r];
                Pl[w][qf * 16 + lg * 4 + r][li]      = (bf16)p0[r];
                Pl[w][qf * 16 + lg * 4 + r][16 + li] = (bf16)p1[r];
            }
        }
        const bf16x8 ap0 = *(const bf16x8*)&Pl[w][li][lg * 8];
        const bf16x8 ap1 = *(const bf16x8*)&Pl[w][16 + li][lg * 8];
        __builtin_amdgcn_s_setprio(1);
        #pragma unroll
        for (int dg = 0; dg < 4; ++dg) {
            const bf16x8 bv = *(const bf16x8*)&Vt[cur][dg * 16 + li][lg * 8];
            oacc[0][dg] = MFMA16(ap0, bv, oacc[0][dg]);
            oacc[1][dg] = MFMA16(ap1, bv, oacc[1][dg]);
        }
        __builtin_amdgcn_s_setprio(0);

        if (kt < 12) {
            const int nxt = cur ^ 1;
            *(u32x4*)&Kl[nxt][srow][scol] = kv;
            bf16x8 t = __builtin_bit_cast(bf16x8, vv);
            #pragma unroll
            for (int e = 0; e < 8; ++e) Vt[nxt][sd8 * 8 + e][sj] = t[e];
        }
    }
    #pragma unroll
    for (int qf = 0; qf < 2; ++qf) {
        #pragma unroll
        for (int r = 0; r < 4; ++r) {
            float lsum = lpart[qf][r];
            lsum += __shfl_xor(lsum, 1);
            lsum += __shfl_xor(lsum, 2);
            lsum += __shfl_xor(lsum, 4);
            lsum += __shfl_xor(lsum, 8);
            const int q = qbase + qf * 16 + lg * 4 + r;
            if (q < NQ) {
                const float inv = 1.f / lsum;
                const size_t off = ((size_t)(b * NQ + q)) * CC + head * HD;
                #pragma unroll
                for (int dg = 0; dg < 4; ++dg)
                    ob[off + dg * 16 + li] = (bf16)(oacc[qf][dg][r] * inv);
            }
        }
    }
}

// ---------------- launcher ----------------
extern "C" void kernel_launch(void* const* d_in, const int* in_sizes, int n_in,
                              void* d_out, int out_size, void* d_ws, size_t ws_size,
                              hipStream_t stream) {
    const float* x     = (const float*)d_in[0];
    const float* Wq    = (const float*)d_in[1];
    const float* Wk    = (const float*)d_in[2];
    const float* Wv    = (const float*)d_in[3];
    const float* Wproj = (const float*)d_in[4];
    const float* bproj = (const float*)d_in[5];
    const float* pqw   = (const float*)d_in[6];
    const float* pkw   = (const float*)d_in[7];
    const float* pvw   = (const float*)d_in[8];
    const float* gq    = (const float*)d_in[9];
    const float* bq    = (const float*)d_in[10];
    const float* gk    = (const float*)d_in[11];
    const float* bk    = (const float*)d_in[12];
    const float* gv    = (const float*)d_in[13];
    const float* bv    = (const float*)d_in[14];

    if (ws_size < 364000000ULL) return;
    char* ws = (char*)d_ws;
    bf16* xb    = (bf16*)(ws);               // [50304][768]
    bf16* wqkv  = (bf16*)(ws + 77266944);    // [2304][768] + wpb contiguous
    bf16* wpb   = (bf16*)(ws + 80805888);    // [768][768]
    bf16* tmpq  = (bf16*)(ws + 81985536);    // [50304][768]
    bf16* tmpkv = (bf16*)(ws + 159252480);   // [25856][1536]
    bf16* qn    = (bf16*)(ws + 238682112);   // [96][1664][64] = 20,447,232
    bf16* kn    = (bf16*)(ws + 259129344);   // [96][416][64]
    bf16* vnb   = (bf16*)(ws + 264241152);   // [96][416][64]
    bf16* ob    = (bf16*)(ws + 269352960);   // [12672][768]
    float* wt   = (float*)(ws + 288817152);  // [3][27][64] f32
    float* Mb   = (float*)(ws + 288837888);  // [1]

    (void)hipFuncSetAttribute((const void*)gemmU,
                              hipFuncAttributeMaxDynamicSharedMemorySize, 131072);
    (void)hipFuncSetAttribute((const void*)gemmF,
                              hipFuncAttributeMaxDynamicSharedMemorySize, 98304);

    prep_all<<<6422, 256, 0, stream>>>(x, Wq, Wk, Wv, Wproj, pqw, pkw, pvw,
                                       gq, bq, gk, bk, xb, wqkv, wt, Mb);

    gemmU<<<1197, 512, 131072, stream>>>(xb, wqkv, tmpq, tmpkv);

    pools_all<<<2760, 256, 0, stream>>>(tmpq, tmpkv, wt, gq, bq, gk, bk, gv, bv,
                                        qn, kn, vnb);

    attn_kernel<<<1248, 256, 0, stream>>>(qn, kn, vnb, ob, Mb);

    gemmF<<<50 * 6, 512, 98304, stream>>>(ob, wpb, (float*)d_out, bproj, 6, MO, MOP);
}